// Round 16
// baseline (129.211 us; speedup 1.0000x reference)
//
#include <hip/hip_runtime.h>
#include <hip/hip_bf16.h>

#define BB 2
#define SS 2048
#define HH 16
#define DD 64
#define DM 1024
#define MM (BB*SS)   // 4096

typedef __attribute__((ext_vector_type(4))) float f32x4;
typedef __attribute__((ext_vector_type(16))) float f32x16;
typedef __attribute__((ext_vector_type(8))) short s16x8;
typedef __attribute__((ext_vector_type(2))) int i32x2;

__device__ __forceinline__ unsigned short f2bf(float f){
  unsigned int u = __float_as_uint(f);
  u += 0x7FFF + ((u >> 16) & 1);   // round-to-nearest-even
  return (unsigned short)(u >> 16);
}

__device__ __forceinline__ f32x4 zero4(){ f32x4 z = {0.f,0.f,0.f,0.f}; return z; }

__device__ __forceinline__ unsigned int cvtpk(float a, float b){
  unsigned int r;
  asm("v_cvt_pk_bf16_f32 %0, %1, %2" : "=v"(r) : "v"(a), "v"(b));
  return r;
}

// async global->LDS, 16B per lane; LDS dest is wave-uniform base + lane*16
__device__ __forceinline__ void gload_lds16(const void* g, void* l){
  __builtin_amdgcn_global_load_lds(
    (const __attribute__((address_space(1))) unsigned int*)g,
    (__attribute__((address_space(3))) unsigned int*)l, 16, 0, 0);
}

// ---------------- weight transpose + f32->bf16:  WT[n][k] = W[k][n] ----------------
__global__ __launch_bounds__(256) void wtrans_kernel(
    const float* __restrict__ Wq, const float* __restrict__ Wk,
    const float* __restrict__ Wv, const float* __restrict__ Wo,
    short* __restrict__ wt){
  __shared__ float tile[64][65];
  const float* src = (blockIdx.y==0)?Wq:(blockIdx.y==1)?Wk:(blockIdx.y==2)?Wv:Wo;
  short* dst = wt + (size_t)blockIdx.y * ((size_t)DM*DM);
  int tk = (blockIdx.x >> 4) * 64;   // rows of W (k)
  int tn = (blockIdx.x & 15) * 64;   // cols of W (n)
  int t = threadIdx.x;
  int r = t >> 2;
  int c4 = (t & 3) << 4;
  const float* p = src + (size_t)(tk + r) * DM + tn + c4;
  #pragma unroll
  for (int i = 0; i < 4; ++i){
    float4 vv = *(const float4*)(p + i*4);
    tile[r][c4 + i*4 + 0] = vv.x;
    tile[r][c4 + i*4 + 1] = vv.y;
    tile[r][c4 + i*4 + 2] = vv.z;
    tile[r][c4 + i*4 + 3] = vv.w;
  }
  __syncthreads();
  s16x8 o0, o1;
  #pragma unroll
  for (int j = 0; j < 8; ++j) o0[j] = (short)f2bf(tile[c4 + j][r]);
  #pragma unroll
  for (int j = 0; j < 8; ++j) o1[j] = (short)f2bf(tile[c4 + 8 + j][r]);
  short* qd = dst + (size_t)(tn + r) * DM + tk + c4;
  *(s16x8*)qd       = o0;
  *(s16x8*)(qd + 8) = o1;
}

// ---------------- GEMM cores ---------------------------------------------------------
#define GEMM_PRE_COMMON() \
  int m0 = blockIdx.x * 128, n0 = blockIdx.y * 64; \
  int t = threadIdx.x; \
  int w = t >> 6, lane = t & 63, g = lane >> 4, c = lane & 15; \
  int wm = (w >> 1) * 64, wn = (w & 1) * 32; \
  f32x4 acc[4][2]; \
  _Pragma("unroll") for (int i=0;i<4;++i) \
    _Pragma("unroll") for (int j=0;j<2;++j) acc[i][j] = zero4(); \
  int srow = t >> 3; \
  int scol = ((t & 7) ^ (srow & 7)) * 8; \
  const short* Bp = BT + (size_t)(n0 + srow) * DM + scol; \
  int rsw = (c & 7) << 4; \
  int adst = srow*128 + (t & 7)*16;

#define BSTAGE(k0_, BB_) { \
  gload_lds16(Bp + (k0_),          (char*)(BB_) + w*1024); \
  gload_lds16(Bp + 32*DM + (k0_),  (char*)(BB_) + 4096 + w*1024); \
}

#define ALOAD_F32(k0_) { \
  _Pragma("unroll") for (int ch=0; ch<4; ++ch){ \
    areg[2*ch]   = *(const float4*)(Apf + (size_t)ch*32*DM + (k0_)); \
    areg[2*ch+1] = *(const float4*)(Apf + (size_t)ch*32*DM + (k0_) + 4); \
  } }

#define AWRITE(AB_) { \
  _Pragma("unroll") for (int ch=0; ch<4; ++ch){ \
    int4 pk4; \
    pk4.x = (int)cvtpk(areg[2*ch].x,   areg[2*ch].y); \
    pk4.y = (int)cvtpk(areg[2*ch].z,   areg[2*ch].w); \
    pk4.z = (int)cvtpk(areg[2*ch+1].x, areg[2*ch+1].y); \
    pk4.w = (int)cvtpk(areg[2*ch+1].z, areg[2*ch+1].w); \
    *(int4*)((char*)(AB_) + ch*4096 + adst) = pk4; \
  } }

#define ASTAGE_BF16(k0_, AB_) { \
  gload_lds16(Apb + (k0_),          (char*)(AB_) + w*1024); \
  gload_lds16(Apb + 32*DM + (k0_),  (char*)(AB_) + 4096  + w*1024); \
  gload_lds16(Apb + 64*DM + (k0_),  (char*)(AB_) + 8192  + w*1024); \
  gload_lds16(Apb + 96*DM + (k0_),  (char*)(AB_) + 12288 + w*1024); \
}

#define GCOMP(AB_, BB_) { \
  s16x8 af[4][2], bfr[2][2]; \
  _Pragma("unroll") for (int mi=0;mi<4;++mi){ \
    const char* arow = (const char*)(AB_) + (wm + mi*16 + c)*128; \
    af[mi][0] = *(const s16x8*)(arow + ((g*16) ^ rsw)); \
    af[mi][1] = *(const s16x8*)(arow + ((64 + g*16) ^ rsw)); \
  } \
  _Pragma("unroll") for (int ni=0;ni<2;++ni){ \
    const char* brow = (const char*)(BB_) + (wn + ni*16 + c)*128; \
    bfr[ni][0] = *(const s16x8*)(brow + ((g*16) ^ rsw)); \
    bfr[ni][1] = *(const s16x8*)(brow + ((64 + g*16) ^ rsw)); \
  } \
  _Pragma("unroll") for (int mi=0;mi<4;++mi) \
    _Pragma("unroll") for (int ni=0;ni<2;++ni){ \
      acc[mi][ni] = __builtin_amdgcn_mfma_f32_16x16x32_bf16(af[mi][0], bfr[ni][0], acc[mi][ni], 0,0,0); \
      acc[mi][ni] = __builtin_amdgcn_mfma_f32_16x16x32_bf16(af[mi][1], bfr[ni][1], acc[mi][ni], 0,0,0); \
    } \
}

#define GEMM_LOOP_F32() \
  float4 areg[8]; \
  ALOAD_F32(0) \
  BSTAGE(0, &Bs[0][0]) \
  AWRITE(&As[0][0]) \
  __syncthreads(); \
  for (int kk = 0; kk < DM; kk += 128){ \
    if (kk + 64 < DM){ ALOAD_F32(kk+64) BSTAGE(kk+64, &Bs[1][0]) } \
    GCOMP(&As[0][0], &Bs[0][0]) \
    if (kk + 64 < DM){ AWRITE(&As[1][0]) } \
    __syncthreads(); \
    if (kk + 128 < DM){ ALOAD_F32(kk+128) BSTAGE(kk+128, &Bs[0][0]) } \
    GCOMP(&As[1][0], &Bs[1][0]) \
    if (kk + 128 < DM){ AWRITE(&As[0][0]) } \
    __syncthreads(); \
  }

#define GEMM_LOOP_BF16() \
  ASTAGE_BF16(0, &As[0][0]) \
  BSTAGE(0, &Bs[0][0]) \
  __syncthreads(); \
  for (int kk = 0; kk < DM; kk += 128){ \
    if (kk + 64 < DM){ ASTAGE_BF16(kk+64, &As[1][0]) BSTAGE(kk+64, &Bs[1][0]) } \
    GCOMP(&As[0][0], &Bs[0][0]) \
    __syncthreads(); \
    if (kk + 128 < DM){ ASTAGE_BF16(kk+128, &As[0][0]) BSTAGE(kk+128, &Bs[0][0]) } \
    GCOMP(&As[1][0], &Bs[1][0]) \
    __syncthreads(); \
  }

// fused Q/K/V projection GEMM: blockIdx.z selects source/weight/bias/epilogue.
// z=0: Qh (scale=qscale), z=1: Kh, z=2: Vt (transposed epilogue).
__global__ __launch_bounds__(256) void gemm_qkv3_kernel(
    const float* __restrict__ qs, const float* __restrict__ ks,
    const float* __restrict__ vs, const short* __restrict__ WT3,
    const float* __restrict__ bq, const float* __restrict__ bk,
    const float* __restrict__ bv,
    short* __restrict__ Qh, short* __restrict__ Kh, short* __restrict__ Vt,
    float qscale){
  __shared__ __align__(16) short As[2][128*64];
  __shared__ __align__(16) short Bs[2][64*64];
  int z = blockIdx.z;
  const float* A    = (z==0) ? qs : (z==1) ? ks : vs;
  const short* BT   = WT3 + (size_t)z * ((size_t)DM*DM);
  const float* bias = (z==0) ? bq : (z==1) ? bk : bv;
  GEMM_PRE_COMMON()
  const float* Apf = A + (size_t)(m0 + srow) * DM + scol;
  GEMM_LOOP_F32()
  if (z < 2){
    short* outh = (z==0) ? Qh : Kh;
    float scale = (z==0) ? qscale : 1.0f;
    #pragma unroll
    for (int ni=0;ni<2;++ni){
      int col = n0 + wn + ni*16 + c;
      float bvv = bias[col];
      int hh = col >> 6, d = col & 63;
      #pragma unroll
      for (int mi=0;mi<4;++mi){
        #pragma unroll
        for (int r=0;r<4;++r){
          int row = m0 + wm + mi*16 + g*4 + r;
          int b = row >> 11, s = row & (SS-1);
          float val = (acc[mi][ni][r] + bvv) * scale;
          outh[((((size_t)b*HH + hh)*SS + s) << 6) + d] = (short)f2bf(val);
        }
      }
    }
  } else {
    #pragma unroll
    for (int ni=0;ni<2;++ni){
      int col = n0 + wn + ni*16 + c;
      float bvv = bias[col];
      int hh = col >> 6, d = col & 63;
      #pragma unroll
      for (int mi=0;mi<4;++mi){
        int row = m0 + wm + mi*16 + g*4;
        int b = row >> 11, s = row & (SS-1);
        i32x2 pk2;
        pk2.x = (int)cvtpk(acc[mi][ni][0] + bvv, acc[mi][ni][1] + bvv);
        pk2.y = (int)cvtpk(acc[mi][ni][2] + bvv, acc[mi][ni][3] + bvv);
        *(i32x2*)(Vt + (((size_t)(b*HH + hh)*64 + d) * SS + s)) = pk2;
      }
    }
  }
}

// output GEMM: bf16 A (gload_lds), f32 out = A @ BT^T + bias
__global__ __launch_bounds__(256) void gemm_out_kernel(
    const short* __restrict__ A, const short* __restrict__ BT,
    const float* __restrict__ bias, float* __restrict__ out){
  __shared__ __align__(16) short As[2][128*64];
  __shared__ __align__(16) short Bs[2][64*64];
  GEMM_PRE_COMMON()
  const short* Apb = A + (size_t)(m0 + srow) * DM + scol;
  GEMM_LOOP_BF16()
  #pragma unroll
  for (int ni=0;ni<2;++ni){
    int col = n0 + wn + ni*16 + c;
    float bvv = bias[col];
    #pragma unroll
    for (int mi=0;mi<4;++mi){
      #pragma unroll
      for (int r=0;r<4;++r){
        int row = m0 + wm + mi*16 + g*4 + r;
        out[(size_t)row * DM + col] = acc[mi][ni][r] + bvv;
      }
    }
  }
}

// ---------------- flash attention: 32x32 MFMA, kv-split + double-buffered -----------
// per (b,h): Q[2048,64] (pre-scaled by 0.125*log2e), K[2048,64], Vt[64,2048].
// 4 waves/block = 2 q-subblocks (wq, 32 q) x 2 kv-streams (wz, 16 tiles each).
// QBLK=64 -> grid 32x32 = 1024 blocks = 4096 waves = 4 waves/SIMD (2x R14).
// 64KB LDS arena, double-buffered per stream (keeps R8/R14's proven
// static-addressing structure; R10's regression was single-buffering):
//   buf b @ b*32768: Kz0 @+0, Kz1 @+8192, Vz0 @+16384, Vz1 @+24576.
// Wave (wq,wz) stages K (wq=0) or V (wq=1) of stream wz: 8 gload_lds/tile.
// Fixed-max softmax => kv-halves merge by pure summation via LDS (R10-proven).
__global__ __launch_bounds__(256) void attn_kernel(
    const short* __restrict__ Qh, const short* __restrict__ Kh,
    const short* __restrict__ Vt, short* __restrict__ Oh){
  __shared__ __align__(16) short SMEM[32768];      // 64 KB
  int bh = blockIdx.y;
  int qb = blockIdx.x * 64;
  int t = threadIdx.x, w = t >> 6, lane = t & 63;
  int lq = lane & 31, h = lane >> 5;
  int wq = w >> 1, wz = w & 1;
  int qrow0 = qb + wq*32;

  // Q B-frags: qf[kc] holds B[k=kc*16+h*8+j][q=lq]
  const short* qg = Qh + (((size_t)bh*SS + qrow0 + lq) << 6) + h*8;
  s16x8 qf[4];
  #pragma unroll
  for (int kc=0;kc<4;++kc) qf[kc] = *(const s16x8*)(qg + kc*16);

  f32x16 z16;
  #pragma unroll
  for (int i=0;i<16;++i) z16[i] = 0.f;
  f32x16 oA, oB;   // O^T acc, d-blocks 0 / 1 (partial over this wave's kv half)
  #pragma unroll
  for (int i=0;i<16;++i){ oA[i]=0.f; oB[i]=0.f; }
  float l = 0.f;
  const char* kbase = (const char*)(Kh + (((size_t)bh*SS) << 6));
  const char* vbase = (const char*)(Vt + ((size_t)bh*64) * SS);

  int rsel = lane >> 3;                         // 0..7
  int csw  = ((lane & 7) << 4) ^ (rsel << 4);   // pre-swizzled source col
  int swr  = (lane & 7) << 4;                   // read swizzle (row&7 == lq&7)

  // loop-invariant per-lane LDS read bases into stream wz, buf 0
  const char* smem = (const char*)&SMEM[0];
  const char* kr0 = smem + wz*8192 + lq*128 + (( 0 + h*16) ^ swr);
  const char* kr1 = smem + wz*8192 + lq*128 + ((32 + h*16) ^ swr);
  const char* kr2 = smem + wz*8192 + lq*128 + ((64 + h*16) ^ swr);
  const char* kr3 = smem + wz*8192 + lq*128 + ((96 + h*16) ^ swr);
  // staging dest base: K stream (wq=0) or V stream (wq=1) of wz, buf 0
  char* sdst = (char*)&SMEM[0] + wz*8192 + wq*16384;

#define STAGE(T, BOFF) { \
    if (wq == 0){ \
      _Pragma("unroll") for (int i=0;i<8;++i){ \
        const char* kg = kbase + (((size_t)((T)*64 + i*8 + rsel)) << 7) + csw; \
        gload_lds16(kg, sdst + (BOFF) + i*1024); \
      } \
    } else { \
      _Pragma("unroll") for (int i=0;i<8;++i){ \
        const char* vg = vbase + (size_t)(i*8 + rsel) * (SS*2) + (((size_t)(T)) << 7) + csw; \
        gload_lds16(vg, sdst + (BOFF) + i*1024); \
      } \
    } }

#define MFMA32(a_, b_, c_) __builtin_amdgcn_mfma_f32_32x32x16_bf16(a_, b_, c_, 0,0,0)

#define TILE(BOFF) { \
    f32x16 sA, sB; \
    s16x8 kf; \
    __builtin_amdgcn_s_setprio(1); \
    kf = *(const s16x8*)(kr0 + (BOFF));        sA = MFMA32(kf, qf[0], z16); \
    kf = *(const s16x8*)(kr0 + (BOFF) + 4096); sB = MFMA32(kf, qf[0], z16); \
    kf = *(const s16x8*)(kr1 + (BOFF));        sA = MFMA32(kf, qf[1], sA); \
    kf = *(const s16x8*)(kr1 + (BOFF) + 4096); sB = MFMA32(kf, qf[1], sB); \
    kf = *(const s16x8*)(kr2 + (BOFF));        sA = MFMA32(kf, qf[2], sA); \
    kf = *(const s16x8*)(kr2 + (BOFF) + 4096); sB = MFMA32(kf, qf[2], sB); \
    kf = *(const s16x8*)(kr3 + (BOFF));        sA = MFMA32(kf, qf[3], sA); \
    kf = *(const s16x8*)(kr3 + (BOFF) + 4096); sB = MFMA32(kf, qf[3], sB); \
    __builtin_amdgcn_s_setprio(0); \
    float lp = 0.f; \
    unsigned int cA[8], cB[8]; \
    _Pragma("unroll") \
    for (int i=0;i<8;++i){ \
      float a0 = __builtin_amdgcn_exp2f(sA[2*i]); \
      float a1 = __builtin_amdgcn_exp2f(sA[2*i+1]); \
      float b0 = __builtin_amdgcn_exp2f(sB[2*i]); \
      float b1 = __builtin_amdgcn_exp2f(sB[2*i+1]); \
      lp += (a0 + a1) + (b0 + b1); \
      cA[i] = cvtpk(a0, a1); \
      cB[i] = cvtpk(b0, b1); \
    } \
    l += lp; \
    asm("v_permlane32_swap_b32 %0, %1" : "+v"(cA[0]), "+v"(cA[2])); \
    asm("v_permlane32_swap_b32 %0, %1" : "+v"(cA[1]), "+v"(cA[3])); \
    asm("v_permlane32_swap_b32 %0, %1" : "+v"(cA[4]), "+v"(cA[6])); \
    asm("v_permlane32_swap_b32 %0, %1" : "+v"(cA[5]), "+v"(cA[7])); \
    asm("v_permlane32_swap_b32 %0, %1" : "+v"(cB[0]), "+v"(cB[2])); \
    asm("v_permlane32_swap_b32 %0, %1" : "+v"(cB[1]), "+v"(cB[3])); \
    asm("v_permlane32_swap_b32 %0, %1" : "+v"(cB[4]), "+v"(cB[6])); \
    asm("v_permlane32_swap_b32 %0, %1" : "+v"(cB[5]), "+v"(cB[7])); \
    s16x8 pbf0, pbf1, pbf2, pbf3; \
    { unsigned int* p0 = (unsigned int*)&pbf0; \
      p0[0]=cA[0]; p0[1]=cA[1]; p0[2]=cA[2]; p0[3]=cA[3]; \
      unsigned int* p1 = (unsigned int*)&pbf1; \
      p1[0]=cA[4]; p1[1]=cA[5]; p1[2]=cA[6]; p1[3]=cA[7]; \
      unsigned int* p2 = (unsigned int*)&pbf2; \
      p2[0]=cB[0]; p2[1]=cB[1]; p2[2]=cB[2]; p2[3]=cB[3]; \
      unsigned int* p3 = (unsigned int*)&pbf3; \
      p3[0]=cB[4]; p3[1]=cB[5]; p3[2]=cB[6]; p3[3]=cB[7]; } \
    __builtin_amdgcn_s_setprio(1); \
    kf = *(const s16x8*)(kr0 + (BOFF) + 16384);        oA = MFMA32(kf, pbf0, oA); \
    kf = *(const s16x8*)(kr0 + (BOFF) + 16384 + 4096); oB = MFMA32(kf, pbf0, oB); \
    kf = *(const s16x8*)(kr1 + (BOFF) + 16384);        oA = MFMA32(kf, pbf1, oA); \
    kf = *(const s16x8*)(kr1 + (BOFF) + 16384 + 4096); oB = MFMA32(kf, pbf1, oB); \
    kf = *(const s16x8*)(kr2 + (BOFF) + 16384);        oA = MFMA32(kf, pbf2, oA); \
    kf = *(const s16x8*)(kr2 + (BOFF) + 16384 + 4096); oB = MFMA32(kf, pbf2, oB); \
    kf = *(const s16x8*)(kr3 + (BOFF) + 16384);        oA = MFMA32(kf, pbf3, oA); \
    kf = *(const s16x8*)(kr3 + (BOFF) + 16384 + 4096); oB = MFMA32(kf, pbf3, oB); \
    __builtin_amdgcn_s_setprio(0); \
  }

  int T0 = wz * 16;
  STAGE(T0, 0)
  __syncthreads();

  for (int tb = 0; tb < 16; tb += 2){
    STAGE(T0 + tb + 1, 32768)       // tb+1 <= 15 always
    TILE(0)
    __syncthreads();
    if (tb + 2 < 16) STAGE(T0 + tb + 2, 0)
    TILE(32768)
    __syncthreads();
  }
#undef STAGE
#undef TILE

  // partial l: lanes h=0/h=1 hold complementary kv rows of this half
  l += __shfl_xor(l, 32);

  // merge kv streams through LDS: wz=1 publishes, wz=0 adds + finalizes.
  // (arena reuse is safe: final loop barrier drained all reads/writes)
  float* shf = (float*)&SMEM[0];
  float* slot = shf + ((size_t)wq*64 + lane) * 33;
  if (wz == 1){
    #pragma unroll
    for (int i=0;i<16;++i) slot[i]      = oA[i];
    #pragma unroll
    for (int i=0;i<16;++i) slot[16 + i] = oB[i];
    slot[32] = l;
  }
  __syncthreads();
  if (wz == 0){
    #pragma unroll
    for (int i=0;i<16;++i) oA[i] += slot[i];
    #pragma unroll
    for (int i=0;i<16;++i) oB[i] += slot[16 + i];
    l += slot[32];
    float inv = 1.f / l;
    int b = bh >> 4, hh = bh & 15;
    short* ob = Oh + (((size_t)(b*SS + qrow0 + lq)) << 10) + hh*64 + 4*h;
    #pragma unroll
    for (int rg=0;rg<4;++rg){
      i32x2 pk;
      pk.x = (int)cvtpk(oA[rg*4+0]*inv, oA[rg*4+1]*inv);
      pk.y = (int)cvtpk(oA[rg*4+2]*inv, oA[rg*4+3]*inv);
      *(i32x2*)(ob + 8*rg) = pk;          // d-block 0: d = 8*rg + 4*h + 0..3
      pk.x = (int)cvtpk(oB[rg*4+0]*inv, oB[rg*4+1]*inv);
      pk.y = (int)cvtpk(oB[rg*4+2]*inv, oB[rg*4+3]*inv);
      *(i32x2*)(ob + 32 + 8*rg) = pk;     // d-block 1
    }
  }
}

extern "C" void kernel_launch(void* const* d_in, const int* in_sizes, int n_in,
                              void* d_out, int out_size, void* d_ws, size_t ws_size,
                              hipStream_t stream){
  const float* q  = (const float*)d_in[0];
  const float* k  = (const float*)d_in[1];
  const float* v  = (const float*)d_in[2];
  const float* Wq = (const float*)d_in[3];
  const float* bq = (const float*)d_in[4];
  const float* Wk = (const float*)d_in[5];
  const float* bk = (const float*)d_in[6];
  const float* Wv = (const float*)d_in[7];
  const float* bv = (const float*)d_in[8];
  const float* Wo = (const float*)d_in[9];
  const float* bo = (const float*)d_in[10];
  (void)in_sizes; (void)n_in; (void)out_size; (void)ws_size;

  short* wsp = (short*)d_ws;
  const size_t MW = 1048576;          // one 1024x1024 bf16 matrix, in elements
  short* WT3 = wsp;                   // WTq, WTk, WTv contiguous
  short* WTo = wsp + 3*MW;
  short* Qh  = wsp + 4*MW;            // [B,H,S,64] bf16 (pre-scaled by 0.125*log2e)
  short* Kh  = wsp + 8*MW;            // [B,H,S,64] bf16
  short* Oh  = wsp + 12*MW;           // attention out [B*S,1024] bf16
  short* Vt  = wsp + 16*MW;           // [B,H,64,S] bf16 (written directly by gemm)

  const float QSCALE = 0.125f * 1.44269504088896f;  // fold 1/sqrt(dk) and log2(e)
  wtrans_kernel<<<dim3(256,4), 256, 0, stream>>>(Wq, Wk, Wv, Wo, wsp);
  gemm_qkv3_kernel<<<dim3(32,16,3), 256, 0, stream>>>(q, k, v, WT3, bq, bk, bv,
                                                      Qh, Kh, Vt, QSCALE);
  attn_kernel<<<dim3(32,32), 256, 0, stream>>>(Qh, Kh, Vt, Oh);
  gemm_out_kernel<<<dim3(32,16), 256, 0, stream>>>(Oh, WTo, bo, (float*)d_out);
}

// Round 17
// 116.752 us; speedup vs baseline: 1.1067x; 1.1067x over previous
//
#include <hip/hip_runtime.h>
#include <hip/hip_bf16.h>

#define BB 2
#define SS 2048
#define HH 16
#define DD 64
#define DM 1024
#define MM (BB*SS)   // 4096

typedef __attribute__((ext_vector_type(4))) float f32x4;
typedef __attribute__((ext_vector_type(16))) float f32x16;
typedef __attribute__((ext_vector_type(8))) short s16x8;
typedef __attribute__((ext_vector_type(2))) int i32x2;

__device__ __forceinline__ unsigned short f2bf(float f){
  unsigned int u = __float_as_uint(f);
  u += 0x7FFF + ((u >> 16) & 1);   // round-to-nearest-even
  return (unsigned short)(u >> 16);
}

__device__ __forceinline__ f32x4 zero4(){ f32x4 z = {0.f,0.f,0.f,0.f}; return z; }

__device__ __forceinline__ unsigned int cvtpk(float a, float b){
  unsigned int r;
  asm("v_cvt_pk_bf16_f32 %0, %1, %2" : "=v"(r) : "v"(a), "v"(b));
  return r;
}

// async global->LDS, 16B per lane; LDS dest is wave-uniform base + lane*16
__device__ __forceinline__ void gload_lds16(const void* g, void* l){
  __builtin_amdgcn_global_load_lds(
    (const __attribute__((address_space(1))) unsigned int*)g,
    (__attribute__((address_space(3))) unsigned int*)l, 16, 0, 0);
}

// ---------------- weight transpose + f32->bf16:  WT[n][k] = W[k][n] ----------------
__global__ __launch_bounds__(256) void wtrans_kernel(
    const float* __restrict__ Wq, const float* __restrict__ Wk,
    const float* __restrict__ Wv, const float* __restrict__ Wo,
    short* __restrict__ wt){
  __shared__ float tile[64][65];
  const float* src = (blockIdx.y==0)?Wq:(blockIdx.y==1)?Wk:(blockIdx.y==2)?Wv:Wo;
  short* dst = wt + (size_t)blockIdx.y * ((size_t)DM*DM);
  int tk = (blockIdx.x >> 4) * 64;   // rows of W (k)
  int tn = (blockIdx.x & 15) * 64;   // cols of W (n)
  int t = threadIdx.x;
  int r = t >> 2;
  int c4 = (t & 3) << 4;
  const float* p = src + (size_t)(tk + r) * DM + tn + c4;
  #pragma unroll
  for (int i = 0; i < 4; ++i){
    float4 vv = *(const float4*)(p + i*4);
    tile[r][c4 + i*4 + 0] = vv.x;
    tile[r][c4 + i*4 + 1] = vv.y;
    tile[r][c4 + i*4 + 2] = vv.z;
    tile[r][c4 + i*4 + 3] = vv.w;
  }
  __syncthreads();
  s16x8 o0, o1;
  #pragma unroll
  for (int j = 0; j < 8; ++j) o0[j] = (short)f2bf(tile[c4 + j][r]);
  #pragma unroll
  for (int j = 0; j < 8; ++j) o1[j] = (short)f2bf(tile[c4 + 8 + j][r]);
  short* qd = dst + (size_t)(tn + r) * DM + tk + c4;
  *(s16x8*)qd       = o0;
  *(s16x8*)(qd + 8) = o1;
}

// ---------------- GEMM cores ---------------------------------------------------------
// Shared pieces. 64-wide-B macros (gemm_out) and 128-wide-B macros (qkv3) coexist;
// both use the proven all-drain-barrier double-buffered loop.

#define ALOAD_F32(k0_) { \
  _Pragma("unroll") for (int ch=0; ch<4; ++ch){ \
    areg[2*ch]   = *(const float4*)(Apf + (size_t)ch*32*DM + (k0_)); \
    areg[2*ch+1] = *(const float4*)(Apf + (size_t)ch*32*DM + (k0_) + 4); \
  } }

#define AWRITE(AB_) { \
  _Pragma("unroll") for (int ch=0; ch<4; ++ch){ \
    int4 pk4; \
    pk4.x = (int)cvtpk(areg[2*ch].x,   areg[2*ch].y); \
    pk4.y = (int)cvtpk(areg[2*ch].z,   areg[2*ch].w); \
    pk4.z = (int)cvtpk(areg[2*ch+1].x, areg[2*ch+1].y); \
    pk4.w = (int)cvtpk(areg[2*ch+1].z, areg[2*ch+1].w); \
    *(int4*)((char*)(AB_) + ch*4096 + adst) = pk4; \
  } }

#define ASTAGE_BF16(k0_, AB_) { \
  gload_lds16(Apb + (k0_),          (char*)(AB_) + w*1024); \
  gload_lds16(Apb + 32*DM + (k0_),  (char*)(AB_) + 4096  + w*1024); \
  gload_lds16(Apb + 64*DM + (k0_),  (char*)(AB_) + 8192  + w*1024); \
  gload_lds16(Apb + 96*DM + (k0_),  (char*)(AB_) + 12288 + w*1024); \
}

// ----- 64-wide-B variant (gemm_out) -----
#define GEMM_PRE_COMMON() \
  int m0 = blockIdx.x * 128, n0 = blockIdx.y * 64; \
  int t = threadIdx.x; \
  int w = t >> 6, lane = t & 63, g = lane >> 4, c = lane & 15; \
  int wm = (w >> 1) * 64, wn = (w & 1) * 32; \
  f32x4 acc[4][2]; \
  _Pragma("unroll") for (int i=0;i<4;++i) \
    _Pragma("unroll") for (int j=0;j<2;++j) acc[i][j] = zero4(); \
  int srow = t >> 3; \
  int scol = ((t & 7) ^ (srow & 7)) * 8; \
  const short* Bp = BT + (size_t)(n0 + srow) * DM + scol; \
  int rsw = (c & 7) << 4; \
  int adst = srow*128 + (t & 7)*16;

#define BSTAGE(k0_, BB_) { \
  gload_lds16(Bp + (k0_),          (char*)(BB_) + w*1024); \
  gload_lds16(Bp + 32*DM + (k0_),  (char*)(BB_) + 4096 + w*1024); \
}

#define GCOMP(AB_, BB_) { \
  s16x8 af[4][2], bfr[2][2]; \
  _Pragma("unroll") for (int mi=0;mi<4;++mi){ \
    const char* arow = (const char*)(AB_) + (wm + mi*16 + c)*128; \
    af[mi][0] = *(const s16x8*)(arow + ((g*16) ^ rsw)); \
    af[mi][1] = *(const s16x8*)(arow + ((64 + g*16) ^ rsw)); \
  } \
  _Pragma("unroll") for (int ni=0;ni<2;++ni){ \
    const char* brow = (const char*)(BB_) + (wn + ni*16 + c)*128; \
    bfr[ni][0] = *(const s16x8*)(brow + ((g*16) ^ rsw)); \
    bfr[ni][1] = *(const s16x8*)(brow + ((64 + g*16) ^ rsw)); \
  } \
  _Pragma("unroll") for (int mi=0;mi<4;++mi) \
    _Pragma("unroll") for (int ni=0;ni<2;++ni){ \
      acc[mi][ni] = __builtin_amdgcn_mfma_f32_16x16x32_bf16(af[mi][0], bfr[ni][0], acc[mi][ni], 0,0,0); \
      acc[mi][ni] = __builtin_amdgcn_mfma_f32_16x16x32_bf16(af[mi][1], bfr[ni][1], acc[mi][ni], 0,0,0); \
    } \
}

#define GEMM_LOOP_BF16() \
  ASTAGE_BF16(0, &As[0][0]) \
  BSTAGE(0, &Bs[0][0]) \
  __syncthreads(); \
  for (int kk = 0; kk < DM; kk += 128){ \
    if (kk + 64 < DM){ ASTAGE_BF16(kk+64, &As[1][0]) BSTAGE(kk+64, &Bs[1][0]) } \
    GCOMP(&As[0][0], &Bs[0][0]) \
    __syncthreads(); \
    if (kk + 128 < DM){ ASTAGE_BF16(kk+128, &As[0][0]) BSTAGE(kk+128, &Bs[0][0]) } \
    GCOMP(&As[1][0], &Bs[1][0]) \
    __syncthreads(); \
  }

// ----- 128-wide-B variant (qkv3, m97 128x128 tile) -----
#define GEMM_PRE_128() \
  int m0 = blockIdx.x * 128, n0 = blockIdx.y * 128; \
  int t = threadIdx.x; \
  int w = t >> 6, lane = t & 63, g = lane >> 4, c = lane & 15; \
  int wm = (w >> 1) * 64, wn = (w & 1) * 64; \
  f32x4 acc[4][4]; \
  _Pragma("unroll") for (int i=0;i<4;++i) \
    _Pragma("unroll") for (int j=0;j<4;++j) acc[i][j] = zero4(); \
  int srow = t >> 3; \
  int scol = ((t & 7) ^ (srow & 7)) * 8; \
  const short* Bp = BT + (size_t)(n0 + srow) * DM + scol; \
  int rsw = (c & 7) << 4; \
  int adst = srow*128 + (t & 7)*16;

#define BSTAGE128(k0_, BB_) { \
  gload_lds16(Bp + (k0_),          (char*)(BB_) + w*1024); \
  gload_lds16(Bp + 32*DM + (k0_),  (char*)(BB_) + 4096  + w*1024); \
  gload_lds16(Bp + 64*DM + (k0_),  (char*)(BB_) + 8192  + w*1024); \
  gload_lds16(Bp + 96*DM + (k0_),  (char*)(BB_) + 12288 + w*1024); \
}

#define GCOMP128(AB_, BB_) { \
  s16x8 af[4][2], bfr[4][2]; \
  _Pragma("unroll") for (int mi=0;mi<4;++mi){ \
    const char* arow = (const char*)(AB_) + (wm + mi*16 + c)*128; \
    af[mi][0] = *(const s16x8*)(arow + ((g*16) ^ rsw)); \
    af[mi][1] = *(const s16x8*)(arow + ((64 + g*16) ^ rsw)); \
  } \
  _Pragma("unroll") for (int ni=0;ni<4;++ni){ \
    const char* brow = (const char*)(BB_) + (wn + ni*16 + c)*128; \
    bfr[ni][0] = *(const s16x8*)(brow + ((g*16) ^ rsw)); \
    bfr[ni][1] = *(const s16x8*)(brow + ((64 + g*16) ^ rsw)); \
  } \
  _Pragma("unroll") for (int mi=0;mi<4;++mi) \
    _Pragma("unroll") for (int ni=0;ni<4;++ni){ \
      acc[mi][ni] = __builtin_amdgcn_mfma_f32_16x16x32_bf16(af[mi][0], bfr[ni][0], acc[mi][ni], 0,0,0); \
      acc[mi][ni] = __builtin_amdgcn_mfma_f32_16x16x32_bf16(af[mi][1], bfr[ni][1], acc[mi][ni], 0,0,0); \
    } \
}

#define GEMM_LOOP_F32_128() \
  float4 areg[8]; \
  ALOAD_F32(0) \
  BSTAGE128(0, &Bs[0][0]) \
  AWRITE(&As[0][0]) \
  __syncthreads(); \
  for (int kk = 0; kk < DM; kk += 128){ \
    if (kk + 64 < DM){ ALOAD_F32(kk+64) BSTAGE128(kk+64, &Bs[1][0]) } \
    GCOMP128(&As[0][0], &Bs[0][0]) \
    if (kk + 64 < DM){ AWRITE(&As[1][0]) } \
    __syncthreads(); \
    if (kk + 128 < DM){ ALOAD_F32(kk+128) BSTAGE128(kk+128, &Bs[0][0]) } \
    GCOMP128(&As[1][0], &Bs[1][0]) \
    if (kk + 128 < DM){ AWRITE(&As[0][0]) } \
    __syncthreads(); \
  }

// fused Q/K/V projection GEMM (128x128 tile): blockIdx.z selects slice.
// z=0: Qh (scale=qscale), z=1: Kh, z=2: Vt (transposed epilogue).
__global__ __launch_bounds__(256) void gemm_qkv3_kernel(
    const float* __restrict__ qs, const float* __restrict__ ks,
    const float* __restrict__ vs, const short* __restrict__ WT3,
    const float* __restrict__ bq, const float* __restrict__ bk,
    const float* __restrict__ bv,
    short* __restrict__ Qh, short* __restrict__ Kh, short* __restrict__ Vt,
    float qscale){
  __shared__ __align__(16) short As[2][128*64];
  __shared__ __align__(16) short Bs[2][128*64];
  int z = blockIdx.z;
  const float* A    = (z==0) ? qs : (z==1) ? ks : vs;
  const short* BT   = WT3 + (size_t)z * ((size_t)DM*DM);
  const float* bias = (z==0) ? bq : (z==1) ? bk : bv;
  GEMM_PRE_128()
  const float* Apf = A + (size_t)(m0 + srow) * DM + scol;
  GEMM_LOOP_F32_128()
  if (z < 2){
    short* outh = (z==0) ? Qh : Kh;
    float scale = (z==0) ? qscale : 1.0f;
    #pragma unroll
    for (int ni=0;ni<4;++ni){
      int col = n0 + wn + ni*16 + c;
      float bvv = bias[col];
      int hh = col >> 6, d = col & 63;
      #pragma unroll
      for (int mi=0;mi<4;++mi){
        #pragma unroll
        for (int r=0;r<4;++r){
          int row = m0 + wm + mi*16 + g*4 + r;
          int b = row >> 11, s = row & (SS-1);
          float val = (acc[mi][ni][r] + bvv) * scale;
          outh[((((size_t)b*HH + hh)*SS + s) << 6) + d] = (short)f2bf(val);
        }
      }
    }
  } else {
    #pragma unroll
    for (int ni=0;ni<4;++ni){
      int col = n0 + wn + ni*16 + c;
      float bvv = bias[col];
      int hh = col >> 6, d = col & 63;
      #pragma unroll
      for (int mi=0;mi<4;++mi){
        int row = m0 + wm + mi*16 + g*4;
        int b = row >> 11, s = row & (SS-1);
        i32x2 pk2;
        pk2.x = (int)cvtpk(acc[mi][ni][0] + bvv, acc[mi][ni][1] + bvv);
        pk2.y = (int)cvtpk(acc[mi][ni][2] + bvv, acc[mi][ni][3] + bvv);
        *(i32x2*)(Vt + (((size_t)(b*HH + hh)*64 + d) * SS + s)) = pk2;
      }
    }
  }
}

// output GEMM: bf16 A (gload_lds), f32 out = A @ BT^T + bias (128x64 tile)
__global__ __launch_bounds__(256) void gemm_out_kernel(
    const short* __restrict__ A, const short* __restrict__ BT,
    const float* __restrict__ bias, float* __restrict__ out){
  __shared__ __align__(16) short As[2][128*64];
  __shared__ __align__(16) short Bs[2][64*64];
  GEMM_PRE_COMMON()
  const short* Apb = A + (size_t)(m0 + srow) * DM + scol;
  GEMM_LOOP_BF16()
  #pragma unroll
  for (int ni=0;ni<2;++ni){
    int col = n0 + wn + ni*16 + c;
    float bvv = bias[col];
    #pragma unroll
    for (int mi=0;mi<4;++mi){
      #pragma unroll
      for (int r=0;r<4;++r){
        int row = m0 + wm + mi*16 + g*4 + r;
        out[(size_t)row * DM + col] = acc[mi][ni][r] + bvv;
      }
    }
  }
}

// ---------------- flash attention: 32x32 MFMA, static LDS addressing, XCD remap -----
// (R15 version, best safe attn: QBLK=128, 4 waves, double-buffered, no pipeline)
__global__ __launch_bounds__(256) void attn_kernel(
    const short* __restrict__ Qh, const short* __restrict__ Kh,
    const short* __restrict__ Vt, short* __restrict__ Oh){
  __shared__ __align__(16) short SMEM[16384];      // 32 KB
  int n = blockIdx.x + (blockIdx.y << 4);
  int bh = (n & 7) | ((n >> 7) << 3);
  int qb = ((n >> 3) & 15) * 128;
  int t = threadIdx.x, w = t >> 6, lane = t & 63;
  int lq = lane & 31, h = lane >> 5;
  int qrow0 = qb + w*32;

  const short* qg = Qh + (((size_t)bh*SS + qrow0 + lq) << 6) + h*8;
  s16x8 qf[4];
  #pragma unroll
  for (int kc=0;kc<4;++kc) qf[kc] = *(const s16x8*)(qg + kc*16);

  f32x16 z16;
  #pragma unroll
  for (int i=0;i<16;++i) z16[i] = 0.f;
  f32x16 oA, oB;
  #pragma unroll
  for (int i=0;i<16;++i){ oA[i]=0.f; oB[i]=0.f; }
  float l = 0.f;
  const char* kbase = (const char*)(Kh + (((size_t)bh*SS) << 6));
  const char* vbase = (const char*)(Vt + ((size_t)bh*64) * SS);

  int rsel = lane >> 3;
  int csw  = ((lane & 7) << 4) ^ (rsel << 4);
  int swr  = (lane & 7) << 4;

  const char* smem = (const char*)&SMEM[0];
  const char* kr0 = smem + lq*128 + (( 0 + h*16) ^ swr);
  const char* kr1 = smem + lq*128 + ((32 + h*16) ^ swr);
  const char* kr2 = smem + lq*128 + ((64 + h*16) ^ swr);
  const char* kr3 = smem + lq*128 + ((96 + h*16) ^ swr);
  char* smem_w = (char*)&SMEM[0] + w*2048;

#define STAGE(T, BOFF) { \
    const char* kg = kbase + (((size_t)((T)*64 + w*16 + rsel)) << 7) + csw; \
    gload_lds16(kg,        smem_w + (BOFF)); \
    gload_lds16(kg + 1024, smem_w + (BOFF) + 1024); \
    const char* vg = vbase + (size_t)(w*16 + rsel) * (SS*2) + ((size_t)(T) << 7) + csw; \
    gload_lds16(vg,            smem_w + (BOFF) + 16384); \
    gload_lds16(vg + 8*(SS*2), smem_w + (BOFF) + 16384 + 1024); \
  }

#define MFMA32(a_, b_, c_) __builtin_amdgcn_mfma_f32_32x32x16_bf16(a_, b_, c_, 0,0,0)

#define TILE(BOFF) { \
    f32x16 sA, sB; \
    s16x8 kf; \
    __builtin_amdgcn_s_setprio(1); \
    kf = *(const s16x8*)(kr0 + (BOFF));        sA = MFMA32(kf, qf[0], z16); \
    kf = *(const s16x8*)(kr0 + (BOFF) + 4096); sB = MFMA32(kf, qf[0], z16); \
    kf = *(const s16x8*)(kr1 + (BOFF));        sA = MFMA32(kf, qf[1], sA); \
    kf = *(const s16x8*)(kr1 + (BOFF) + 4096); sB = MFMA32(kf, qf[1], sB); \
    kf = *(const s16x8*)(kr2 + (BOFF));        sA = MFMA32(kf, qf[2], sA); \
    kf = *(const s16x8*)(kr2 + (BOFF) + 4096); sB = MFMA32(kf, qf[2], sB); \
    kf = *(const s16x8*)(kr3 + (BOFF));        sA = MFMA32(kf, qf[3], sA); \
    kf = *(const s16x8*)(kr3 + (BOFF) + 4096); sB = MFMA32(kf, qf[3], sB); \
    __builtin_amdgcn_s_setprio(0); \
    float lp = 0.f; \
    unsigned int cA[8], cB[8]; \
    _Pragma("unroll") \
    for (int i=0;i<8;++i){ \
      float a0 = __builtin_amdgcn_exp2f(sA[2*i]); \
      float a1 = __builtin_amdgcn_exp2f(sA[2*i+1]); \
      float b0 = __builtin_amdgcn_exp2f(sB[2*i]); \
      float b1 = __builtin_amdgcn_exp2f(sB[2*i+1]); \
      lp += (a0 + a1) + (b0 + b1); \
      cA[i] = cvtpk(a0, a1); \
      cB[i] = cvtpk(b0, b1); \
    } \
    l += lp; \
    asm("v_permlane32_swap_b32 %0, %1" : "+v"(cA[0]), "+v"(cA[2])); \
    asm("v_permlane32_swap_b32 %0, %1" : "+v"(cA[1]), "+v"(cA[3])); \
    asm("v_permlane32_swap_b32 %0, %1" : "+v"(cA[4]), "+v"(cA[6])); \
    asm("v_permlane32_swap_b32 %0, %1" : "+v"(cA[5]), "+v"(cA[7])); \
    asm("v_permlane32_swap_b32 %0, %1" : "+v"(cB[0]), "+v"(cB[2])); \
    asm("v_permlane32_swap_b32 %0, %1" : "+v"(cB[1]), "+v"(cB[3])); \
    asm("v_permlane32_swap_b32 %0, %1" : "+v"(cB[4]), "+v"(cB[6])); \
    asm("v_permlane32_swap_b32 %0, %1" : "+v"(cB[5]), "+v"(cB[7])); \
    s16x8 pbf0, pbf1, pbf2, pbf3; \
    { unsigned int* p0 = (unsigned int*)&pbf0; \
      p0[0]=cA[0]; p0[1]=cA[1]; p0[2]=cA[2]; p0[3]=cA[3]; \
      unsigned int* p1 = (unsigned int*)&pbf1; \
      p1[0]=cA[4]; p1[1]=cA[5]; p1[2]=cA[6]; p1[3]=cA[7]; \
      unsigned int* p2 = (unsigned int*)&pbf2; \
      p2[0]=cB[0]; p2[1]=cB[1]; p2[2]=cB[2]; p2[3]=cB[3]; \
      unsigned int* p3 = (unsigned int*)&pbf3; \
      p3[0]=cB[4]; p3[1]=cB[5]; p3[2]=cB[6]; p3[3]=cB[7]; } \
    __builtin_amdgcn_s_setprio(1); \
    kf = *(const s16x8*)(kr0 + (BOFF) + 16384);        oA = MFMA32(kf, pbf0, oA); \
    kf = *(const s16x8*)(kr0 + (BOFF) + 16384 + 4096); oB = MFMA32(kf, pbf0, oB); \
    kf = *(const s16x8*)(kr1 + (BOFF) + 16384);        oA = MFMA32(kf, pbf1, oA); \
    kf = *(const s16x8*)(kr1 + (BOFF) + 16384 + 4096); oB = MFMA32(kf, pbf1, oB); \
    kf = *(const s16x8*)(kr2 + (BOFF) + 16384);        oA = MFMA32(kf, pbf2, oA); \
    kf = *(const s16x8*)(kr2 + (BOFF) + 16384 + 4096); oB = MFMA32(kf, pbf2, oB); \
    kf = *(const s16x8*)(kr3 + (BOFF) + 16384);        oA = MFMA32(kf, pbf3, oA); \
    kf = *(const s16x8*)(kr3 + (BOFF) + 16384 + 4096); oB = MFMA32(kf, pbf3, oB); \
    __builtin_amdgcn_s_setprio(0); \
  }

  STAGE(0, 0)
  __syncthreads();

  for (int tb = 0; tb < 32; tb += 2){
    STAGE(tb+1, 8192)          // tb+1 <= 31 always
    TILE(0)
    __syncthreads();
    if (tb + 2 < 32) STAGE(tb+2, 0)
    TILE(8192)
    __syncthreads();
  }
#undef STAGE
#undef TILE

  l += __shfl_xor(l, 32);
  float inv = 1.f / l;
  int b = bh >> 4, hh = bh & 15;
  short* ob = Oh + (((size_t)(b*SS + qrow0 + lq)) << 10) + hh*64 + 4*h;
  #pragma unroll
  for (int rg=0;rg<4;++rg){
    i32x2 pk;
    pk.x = (int)cvtpk(oA[rg*4+0]*inv, oA[rg*4+1]*inv);
    pk.y = (int)cvtpk(oA[rg*4+2]*inv, oA[rg*4+3]*inv);
    *(i32x2*)(ob + 8*rg) = pk;          // d-block 0: d = 8*rg + 4*h + 0..3
    pk.x = (int)cvtpk(oB[rg*4+0]*inv, oB[rg*4+1]*inv);
    pk.y = (int)cvtpk(oB[rg*4+2]*inv, oB[rg*4+3]*inv);
    *(i32x2*)(ob + 32 + 8*rg) = pk;     // d-block 1
  }
}

extern "C" void kernel_launch(void* const* d_in, const int* in_sizes, int n_in,
                              void* d_out, int out_size, void* d_ws, size_t ws_size,
                              hipStream_t stream){
  const float* q  = (const float*)d_in[0];
  const float* k  = (const float*)d_in[1];
  const float* v  = (const float*)d_in[2];
  const float* Wq = (const float*)d_in[3];
  const float* bq = (const float*)d_in[4];
  const float* Wk = (const float*)d_in[5];
  const float* bk = (const float*)d_in[6];
  const float* Wv = (const float*)d_in[7];
  const float* bv = (const float*)d_in[8];
  const float* Wo = (const float*)d_in[9];
  const float* bo = (const float*)d_in[10];
  (void)in_sizes; (void)n_in; (void)out_size; (void)ws_size;

  short* wsp = (short*)d_ws;
  const size_t MW = 1048576;          // one 1024x1024 bf16 matrix, in elements
  short* WT3 = wsp;                   // WTq, WTk, WTv contiguous
  short* WTo = wsp + 3*MW;
  short* Qh  = wsp + 4*MW;            // [B,H,S,64] bf16 (pre-scaled by 0.125*log2e)
  short* Kh  = wsp + 8*MW;            // [B,H,S,64] bf16
  short* Oh  = wsp + 12*MW;           // attention out [B*S,1024] bf16
  short* Vt  = wsp + 16*MW;           // [B,H,64,S] bf16 (written directly by gemm)

  const float QSCALE = 0.125f * 1.44269504088896f;  // fold 1/sqrt(dk) and log2(e)
  wtrans_kernel<<<dim3(256,4), 256, 0, stream>>>(Wq, Wk, Wv, Wo, wsp);
  gemm_qkv3_kernel<<<dim3(32,8,3), 256, 0, stream>>>(q, k, v, WT3, bq, bk, bv,
                                                     Qh, Kh, Vt, QSCALE);
  attn_kernel<<<dim3(16,32), 256, 0, stream>>>(Qh, Kh, Vt, Oh);
  gemm_out_kernel<<<dim3(32,16), 256, 0, stream>>>(Oh, WTo, bo, (float*)d_out);
}

// Round 18
// 115.840 us; speedup vs baseline: 1.1154x; 1.0079x over previous
//
#include <hip/hip_runtime.h>
#include <hip/hip_bf16.h>

#define BB 2
#define SS 2048
#define HH 16
#define DD 64
#define DM 1024
#define MM (BB*SS)   // 4096

typedef __attribute__((ext_vector_type(4))) float f32x4;
typedef __attribute__((ext_vector_type(16))) float f32x16;
typedef __attribute__((ext_vector_type(8))) short s16x8;
typedef __attribute__((ext_vector_type(2))) int i32x2;

__device__ __forceinline__ unsigned short f2bf(float f){
  unsigned int u = __float_as_uint(f);
  u += 0x7FFF + ((u >> 16) & 1);   // round-to-nearest-even
  return (unsigned short)(u >> 16);
}

__device__ __forceinline__ f32x4 zero4(){ f32x4 z = {0.f,0.f,0.f,0.f}; return z; }

__device__ __forceinline__ unsigned int cvtpk(float a, float b){
  unsigned int r;
  asm("v_cvt_pk_bf16_f32 %0, %1, %2" : "=v"(r) : "v"(a), "v"(b));
  return r;
}

// async global->LDS, 16B per lane; LDS dest is wave-uniform base + lane*16
__device__ __forceinline__ void gload_lds16(const void* g, void* l){
  __builtin_amdgcn_global_load_lds(
    (const __attribute__((address_space(1))) unsigned int*)g,
    (__attribute__((address_space(3))) unsigned int*)l, 16, 0, 0);
}

// ---------------- weight transpose + f32->bf16:  WT[n][k] = W[k][n] ----------------
__global__ __launch_bounds__(256) void wtrans_kernel(
    const float* __restrict__ Wq, const float* __restrict__ Wk,
    const float* __restrict__ Wv, const float* __restrict__ Wo,
    short* __restrict__ wt){
  __shared__ float tile[64][65];
  const float* src = (blockIdx.y==0)?Wq:(blockIdx.y==1)?Wk:(blockIdx.y==2)?Wv:Wo;
  short* dst = wt + (size_t)blockIdx.y * ((size_t)DM*DM);
  int tk = (blockIdx.x >> 4) * 64;   // rows of W (k)
  int tn = (blockIdx.x & 15) * 64;   // cols of W (n)
  int t = threadIdx.x;
  int r = t >> 2;
  int c4 = (t & 3) << 4;
  const float* p = src + (size_t)(tk + r) * DM + tn + c4;
  #pragma unroll
  for (int i = 0; i < 4; ++i){
    float4 vv = *(const float4*)(p + i*4);
    tile[r][c4 + i*4 + 0] = vv.x;
    tile[r][c4 + i*4 + 1] = vv.y;
    tile[r][c4 + i*4 + 2] = vv.z;
    tile[r][c4 + i*4 + 3] = vv.w;
  }
  __syncthreads();
  s16x8 o0, o1;
  #pragma unroll
  for (int j = 0; j < 8; ++j) o0[j] = (short)f2bf(tile[c4 + j][r]);
  #pragma unroll
  for (int j = 0; j < 8; ++j) o1[j] = (short)f2bf(tile[c4 + 8 + j][r]);
  short* qd = dst + (size_t)(tn + r) * DM + tk + c4;
  *(s16x8*)qd       = o0;
  *(s16x8*)(qd + 8) = o1;
}

// ---------------- GEMM cores ---------------------------------------------------------
#define ALOAD_F32(k0_) { \
  _Pragma("unroll") for (int ch=0; ch<4; ++ch){ \
    areg[2*ch]   = *(const float4*)(Apf + (size_t)ch*32*DM + (k0_)); \
    areg[2*ch+1] = *(const float4*)(Apf + (size_t)ch*32*DM + (k0_) + 4); \
  } }

#define AWRITE(AB_) { \
  _Pragma("unroll") for (int ch=0; ch<4; ++ch){ \
    int4 pk4; \
    pk4.x = (int)cvtpk(areg[2*ch].x,   areg[2*ch].y); \
    pk4.y = (int)cvtpk(areg[2*ch].z,   areg[2*ch].w); \
    pk4.z = (int)cvtpk(areg[2*ch+1].x, areg[2*ch+1].y); \
    pk4.w = (int)cvtpk(areg[2*ch+1].z, areg[2*ch+1].w); \
    *(int4*)((char*)(AB_) + ch*4096 + adst) = pk4; \
  } }

#define ASTAGE_BF16(k0_, AB_) { \
  gload_lds16(Apb + (k0_),          (char*)(AB_) + w*1024); \
  gload_lds16(Apb + 32*DM + (k0_),  (char*)(AB_) + 4096  + w*1024); \
  gload_lds16(Apb + 64*DM + (k0_),  (char*)(AB_) + 8192  + w*1024); \
  gload_lds16(Apb + 96*DM + (k0_),  (char*)(AB_) + 12288 + w*1024); \
}

// ----- 64-wide-B variant (gemm_out) -----
#define GEMM_PRE_COMMON() \
  int m0 = blockIdx.x * 128, n0 = blockIdx.y * 64; \
  int t = threadIdx.x; \
  int w = t >> 6, lane = t & 63, g = lane >> 4, c = lane & 15; \
  int wm = (w >> 1) * 64, wn = (w & 1) * 32; \
  f32x4 acc[4][2]; \
  _Pragma("unroll") for (int i=0;i<4;++i) \
    _Pragma("unroll") for (int j=0;j<2;++j) acc[i][j] = zero4(); \
  int srow = t >> 3; \
  int scol = ((t & 7) ^ (srow & 7)) * 8; \
  const short* Bp = BT + (size_t)(n0 + srow) * DM + scol; \
  int rsw = (c & 7) << 4; \
  int adst = srow*128 + (t & 7)*16;

#define BSTAGE(k0_, BB_) { \
  gload_lds16(Bp + (k0_),          (char*)(BB_) + w*1024); \
  gload_lds16(Bp + 32*DM + (k0_),  (char*)(BB_) + 4096 + w*1024); \
}

#define GCOMP(AB_, BB_) { \
  s16x8 af[4][2], bfr[2][2]; \
  _Pragma("unroll") for (int mi=0;mi<4;++mi){ \
    const char* arow = (const char*)(AB_) + (wm + mi*16 + c)*128; \
    af[mi][0] = *(const s16x8*)(arow + ((g*16) ^ rsw)); \
    af[mi][1] = *(const s16x8*)(arow + ((64 + g*16) ^ rsw)); \
  } \
  _Pragma("unroll") for (int ni=0;ni<2;++ni){ \
    const char* brow = (const char*)(BB_) + (wn + ni*16 + c)*128; \
    bfr[ni][0] = *(const s16x8*)(brow + ((g*16) ^ rsw)); \
    bfr[ni][1] = *(const s16x8*)(brow + ((64 + g*16) ^ rsw)); \
  } \
  _Pragma("unroll") for (int mi=0;mi<4;++mi) \
    _Pragma("unroll") for (int ni=0;ni<2;++ni){ \
      acc[mi][ni] = __builtin_amdgcn_mfma_f32_16x16x32_bf16(af[mi][0], bfr[ni][0], acc[mi][ni], 0,0,0); \
      acc[mi][ni] = __builtin_amdgcn_mfma_f32_16x16x32_bf16(af[mi][1], bfr[ni][1], acc[mi][ni], 0,0,0); \
    } \
}

#define GEMM_LOOP_BF16() \
  ASTAGE_BF16(0, &As[0][0]) \
  BSTAGE(0, &Bs[0][0]) \
  __syncthreads(); \
  for (int kk = 0; kk < DM; kk += 128){ \
    if (kk + 64 < DM){ ASTAGE_BF16(kk+64, &As[1][0]) BSTAGE(kk+64, &Bs[1][0]) } \
    GCOMP(&As[0][0], &Bs[0][0]) \
    __syncthreads(); \
    if (kk + 128 < DM){ ASTAGE_BF16(kk+128, &As[0][0]) BSTAGE(kk+128, &Bs[0][0]) } \
    GCOMP(&As[1][0], &Bs[1][0]) \
    __syncthreads(); \
  }

// ----- 128-wide-B variant (qkv3, m97 128x128 tile) -----
#define GEMM_PRE_128() \
  int m0 = blockIdx.x * 128, n0 = blockIdx.y * 128; \
  int t = threadIdx.x; \
  int w = t >> 6, lane = t & 63, g = lane >> 4, c = lane & 15; \
  int wm = (w >> 1) * 64, wn = (w & 1) * 64; \
  f32x4 acc[4][4]; \
  _Pragma("unroll") for (int i=0;i<4;++i) \
    _Pragma("unroll") for (int j=0;j<4;++j) acc[i][j] = zero4(); \
  int srow = t >> 3; \
  int scol = ((t & 7) ^ (srow & 7)) * 8; \
  const short* Bp = BT + (size_t)(n0 + srow) * DM + scol; \
  int rsw = (c & 7) << 4; \
  int adst = srow*128 + (t & 7)*16;

#define BSTAGE128(k0_, BB_) { \
  gload_lds16(Bp + (k0_),          (char*)(BB_) + w*1024); \
  gload_lds16(Bp + 32*DM + (k0_),  (char*)(BB_) + 4096  + w*1024); \
  gload_lds16(Bp + 64*DM + (k0_),  (char*)(BB_) + 8192  + w*1024); \
  gload_lds16(Bp + 96*DM + (k0_),  (char*)(BB_) + 12288 + w*1024); \
}

#define GCOMP128(AB_, BB_) { \
  s16x8 af[4][2], bfr[4][2]; \
  _Pragma("unroll") for (int mi=0;mi<4;++mi){ \
    const char* arow = (const char*)(AB_) + (wm + mi*16 + c)*128; \
    af[mi][0] = *(const s16x8*)(arow + ((g*16) ^ rsw)); \
    af[mi][1] = *(const s16x8*)(arow + ((64 + g*16) ^ rsw)); \
  } \
  _Pragma("unroll") for (int ni=0;ni<4;++ni){ \
    const char* brow = (const char*)(BB_) + (wn + ni*16 + c)*128; \
    bfr[ni][0] = *(const s16x8*)(brow + ((g*16) ^ rsw)); \
    bfr[ni][1] = *(const s16x8*)(brow + ((64 + g*16) ^ rsw)); \
  } \
  _Pragma("unroll") for (int mi=0;mi<4;++mi) \
    _Pragma("unroll") for (int ni=0;ni<4;++ni){ \
      acc[mi][ni] = __builtin_amdgcn_mfma_f32_16x16x32_bf16(af[mi][0], bfr[ni][0], acc[mi][ni], 0,0,0); \
      acc[mi][ni] = __builtin_amdgcn_mfma_f32_16x16x32_bf16(af[mi][1], bfr[ni][1], acc[mi][ni], 0,0,0); \
    } \
}

#define GEMM_LOOP_F32_128() \
  float4 areg[8]; \
  ALOAD_F32(0) \
  BSTAGE128(0, &Bs[0][0]) \
  AWRITE(&As[0][0]) \
  __syncthreads(); \
  for (int kk = 0; kk < DM; kk += 128){ \
    if (kk + 64 < DM){ ALOAD_F32(kk+64) BSTAGE128(kk+64, &Bs[1][0]) } \
    GCOMP128(&As[0][0], &Bs[0][0]) \
    if (kk + 64 < DM){ AWRITE(&As[1][0]) } \
    __syncthreads(); \
    if (kk + 128 < DM){ ALOAD_F32(kk+128) BSTAGE128(kk+128, &Bs[0][0]) } \
    GCOMP128(&As[1][0], &Bs[1][0]) \
    if (kk + 128 < DM){ AWRITE(&As[0][0]) } \
    __syncthreads(); \
  }

// fused Q/K/V projection GEMM (128x128 tile): blockIdx.z selects slice.
// z=0: Qh (scale=qscale), z=1: Kh, z=2: Vt (transposed epilogue).
__global__ __launch_bounds__(256) void gemm_qkv3_kernel(
    const float* __restrict__ qs, const float* __restrict__ ks,
    const float* __restrict__ vs, const short* __restrict__ WT3,
    const float* __restrict__ bq, const float* __restrict__ bk,
    const float* __restrict__ bv,
    short* __restrict__ Qh, short* __restrict__ Kh, short* __restrict__ Vt,
    float qscale){
  __shared__ __align__(16) short As[2][128*64];
  __shared__ __align__(16) short Bs[2][128*64];
  int z = blockIdx.z;
  const float* A    = (z==0) ? qs : (z==1) ? ks : vs;
  const short* BT   = WT3 + (size_t)z * ((size_t)DM*DM);
  const float* bias = (z==0) ? bq : (z==1) ? bk : bv;
  GEMM_PRE_128()
  const float* Apf = A + (size_t)(m0 + srow) * DM + scol;
  GEMM_LOOP_F32_128()
  if (z < 2){
    short* outh = (z==0) ? Qh : Kh;
    float scale = (z==0) ? qscale : 1.0f;
    #pragma unroll
    for (int ni=0;ni<4;++ni){
      int col = n0 + wn + ni*16 + c;
      float bvv = bias[col];
      int hh = col >> 6, d = col & 63;
      #pragma unroll
      for (int mi=0;mi<4;++mi){
        #pragma unroll
        for (int r=0;r<4;++r){
          int row = m0 + wm + mi*16 + g*4 + r;
          int b = row >> 11, s = row & (SS-1);
          float val = (acc[mi][ni][r] + bvv) * scale;
          outh[((((size_t)b*HH + hh)*SS + s) << 6) + d] = (short)f2bf(val);
        }
      }
    }
  } else {
    #pragma unroll
    for (int ni=0;ni<4;++ni){
      int col = n0 + wn + ni*16 + c;
      float bvv = bias[col];
      int hh = col >> 6, d = col & 63;
      #pragma unroll
      for (int mi=0;mi<4;++mi){
        int row = m0 + wm + mi*16 + g*4;
        int b = row >> 11, s = row & (SS-1);
        i32x2 pk2;
        pk2.x = (int)cvtpk(acc[mi][ni][0] + bvv, acc[mi][ni][1] + bvv);
        pk2.y = (int)cvtpk(acc[mi][ni][2] + bvv, acc[mi][ni][3] + bvv);
        *(i32x2*)(Vt + (((size_t)(b*HH + hh)*64 + d) * SS + s)) = pk2;
      }
    }
  }
}

// output GEMM: bf16 A (gload_lds), f32 out = A @ BT^T + bias (128x64 tile)
__global__ __launch_bounds__(256) void gemm_out_kernel(
    const short* __restrict__ A, const short* __restrict__ BT,
    const float* __restrict__ bias, float* __restrict__ out){
  __shared__ __align__(16) short As[2][128*64];
  __shared__ __align__(16) short Bs[2][64*64];
  GEMM_PRE_COMMON()
  const short* Apb = A + (size_t)(m0 + srow) * DM + scol;
  GEMM_LOOP_BF16()
  #pragma unroll
  for (int ni=0;ni<2;++ni){
    int col = n0 + wn + ni*16 + c;
    float bvv = bias[col];
    #pragma unroll
    for (int mi=0;mi<4;++mi){
      #pragma unroll
      for (int r=0;r<4;++r){
        int row = m0 + wm + mi*16 + g*4 + r;
        out[(size_t)row * DM + col] = acc[mi][ni][r] + bvv;
      }
    }
  }
}

// ---------------- flash attention: 32x32 MFMA, quad-buffered, XCD remap -------------
// per (b,h): Q[2048,64] (pre-scaled by 0.125*log2e), K[2048,64], Vt[64,2048].
// 4 waves/block, 32 q per wave (QBLK=128), KVBLK=64, grid 16x32 (remapped).
// 64KB LDS arena, QUAD-buffered: K bufs @0,8K,16K,24K; V bufs @32K,40K,48K,56K.
// Schedule: {STAGE(t+2),STAGE(t+3); TILE(t);TILE(t+1); barrier} -- each stage has
// ~2 tiles (~1200cy) to land and barrier count halves vs double-buffer. Same
// all-drain-barrier family as R8/R14/R15 (phase-disjoint buffers, static offsets).
// Occupancy unchanged: grid 512 = 2 blocks/CU; 2 x 64KB = 128KB <= 160KB.
__global__ __launch_bounds__(256) void attn_kernel(
    const short* __restrict__ Qh, const short* __restrict__ Kh,
    const short* __restrict__ Vt, short* __restrict__ Oh){
  __shared__ __align__(16) short SMEM[32768];      // 64 KB
  int n = blockIdx.x + (blockIdx.y << 4);
  int bh = (n & 7) | ((n >> 7) << 3);
  int qb = ((n >> 3) & 15) * 128;
  int t = threadIdx.x, w = t >> 6, lane = t & 63;
  int lq = lane & 31, h = lane >> 5;
  int qrow0 = qb + w*32;

  const short* qg = Qh + (((size_t)bh*SS + qrow0 + lq) << 6) + h*8;
  s16x8 qf[4];
  #pragma unroll
  for (int kc=0;kc<4;++kc) qf[kc] = *(const s16x8*)(qg + kc*16);

  f32x16 z16;
  #pragma unroll
  for (int i=0;i<16;++i) z16[i] = 0.f;
  f32x16 oA, oB;
  #pragma unroll
  for (int i=0;i<16;++i){ oA[i]=0.f; oB[i]=0.f; }
  float l = 0.f;
  const char* kbase = (const char*)(Kh + (((size_t)bh*SS) << 6));
  const char* vbase = (const char*)(Vt + ((size_t)bh*64) * SS);

  int rsel = lane >> 3;
  int csw  = ((lane & 7) << 4) ^ (rsel << 4);
  int swr  = (lane & 7) << 4;

  const char* smem = (const char*)&SMEM[0];
  const char* kr0 = smem + lq*128 + (( 0 + h*16) ^ swr);
  const char* kr1 = smem + lq*128 + ((32 + h*16) ^ swr);
  const char* kr2 = smem + lq*128 + ((64 + h*16) ^ swr);
  const char* kr3 = smem + lq*128 + ((96 + h*16) ^ swr);
  char* smem_w = (char*)&SMEM[0] + w*2048;

#define STAGE(T, KOFF) { \
    const char* kg = kbase + (((size_t)((T)*64 + w*16 + rsel)) << 7) + csw; \
    gload_lds16(kg,        smem_w + (KOFF)); \
    gload_lds16(kg + 1024, smem_w + (KOFF) + 1024); \
    const char* vg = vbase + (size_t)(w*16 + rsel) * (SS*2) + ((size_t)(T) << 7) + csw; \
    gload_lds16(vg,            smem_w + (KOFF) + 32768); \
    gload_lds16(vg + 8*(SS*2), smem_w + (KOFF) + 32768 + 1024); \
  }

#define MFMA32(a_, b_, c_) __builtin_amdgcn_mfma_f32_32x32x16_bf16(a_, b_, c_, 0,0,0)

#define TILE(KOFF) { \
    f32x16 sA, sB; \
    s16x8 kf; \
    __builtin_amdgcn_s_setprio(1); \
    kf = *(const s16x8*)(kr0 + (KOFF));        sA = MFMA32(kf, qf[0], z16); \
    kf = *(const s16x8*)(kr0 + (KOFF) + 4096); sB = MFMA32(kf, qf[0], z16); \
    kf = *(const s16x8*)(kr1 + (KOFF));        sA = MFMA32(kf, qf[1], sA); \
    kf = *(const s16x8*)(kr1 + (KOFF) + 4096); sB = MFMA32(kf, qf[1], sB); \
    kf = *(const s16x8*)(kr2 + (KOFF));        sA = MFMA32(kf, qf[2], sA); \
    kf = *(const s16x8*)(kr2 + (KOFF) + 4096); sB = MFMA32(kf, qf[2], sB); \
    kf = *(const s16x8*)(kr3 + (KOFF));        sA = MFMA32(kf, qf[3], sA); \
    kf = *(const s16x8*)(kr3 + (KOFF) + 4096); sB = MFMA32(kf, qf[3], sB); \
    __builtin_amdgcn_s_setprio(0); \
    float lp = 0.f; \
    unsigned int cA[8], cB[8]; \
    _Pragma("unroll") \
    for (int i=0;i<8;++i){ \
      float a0 = __builtin_amdgcn_exp2f(sA[2*i]); \
      float a1 = __builtin_amdgcn_exp2f(sA[2*i+1]); \
      float b0 = __builtin_amdgcn_exp2f(sB[2*i]); \
      float b1 = __builtin_amdgcn_exp2f(sB[2*i+1]); \
      lp += (a0 + a1) + (b0 + b1); \
      cA[i] = cvtpk(a0, a1); \
      cB[i] = cvtpk(b0, b1); \
    } \
    l += lp; \
    asm("v_permlane32_swap_b32 %0, %1" : "+v"(cA[0]), "+v"(cA[2])); \
    asm("v_permlane32_swap_b32 %0, %1" : "+v"(cA[1]), "+v"(cA[3])); \
    asm("v_permlane32_swap_b32 %0, %1" : "+v"(cA[4]), "+v"(cA[6])); \
    asm("v_permlane32_swap_b32 %0, %1" : "+v"(cA[5]), "+v"(cA[7])); \
    asm("v_permlane32_swap_b32 %0, %1" : "+v"(cB[0]), "+v"(cB[2])); \
    asm("v_permlane32_swap_b32 %0, %1" : "+v"(cB[1]), "+v"(cB[3])); \
    asm("v_permlane32_swap_b32 %0, %1" : "+v"(cB[4]), "+v"(cB[6])); \
    asm("v_permlane32_swap_b32 %0, %1" : "+v"(cB[5]), "+v"(cB[7])); \
    s16x8 pbf0, pbf1, pbf2, pbf3; \
    { unsigned int* p0 = (unsigned int*)&pbf0; \
      p0[0]=cA[0]; p0[1]=cA[1]; p0[2]=cA[2]; p0[3]=cA[3]; \
      unsigned int* p1 = (unsigned int*)&pbf1; \
      p1[0]=cA[4]; p1[1]=cA[5]; p1[2]=cA[6]; p1[3]=cA[7]; \
      unsigned int* p2 = (unsigned int*)&pbf2; \
      p2[0]=cB[0]; p2[1]=cB[1]; p2[2]=cB[2]; p2[3]=cB[3]; \
      unsigned int* p3 = (unsigned int*)&pbf3; \
      p3[0]=cB[4]; p3[1]=cB[5]; p3[2]=cB[6]; p3[3]=cB[7]; } \
    __builtin_amdgcn_s_setprio(1); \
    kf = *(const s16x8*)(kr0 + (KOFF) + 32768);        oA = MFMA32(kf, pbf0, oA); \
    kf = *(const s16x8*)(kr0 + (KOFF) + 32768 + 4096); oB = MFMA32(kf, pbf0, oB); \
    kf = *(const s16x8*)(kr1 + (KOFF) + 32768);        oA = MFMA32(kf, pbf1, oA); \
    kf = *(const s16x8*)(kr1 + (KOFF) + 32768 + 4096); oB = MFMA32(kf, pbf1, oB); \
    kf = *(const s16x8*)(kr2 + (KOFF) + 32768);        oA = MFMA32(kf, pbf2, oA); \
    kf = *(const s16x8*)(kr2 + (KOFF) + 32768 + 4096); oB = MFMA32(kf, pbf2, oB); \
    kf = *(const s16x8*)(kr3 + (KOFF) + 32768);        oA = MFMA32(kf, pbf3, oA); \
    kf = *(const s16x8*)(kr3 + (KOFF) + 32768 + 4096); oB = MFMA32(kf, pbf3, oB); \
    __builtin_amdgcn_s_setprio(0); \
  }

  // prologue: tiles 0,1 into bufs 0,1
  STAGE(0, 0)
  STAGE(1, 8192)
  __syncthreads();

  for (int tb = 0; tb < 32; tb += 4){
    if (tb + 2 < 32) STAGE(tb+2, 16384)
    if (tb + 3 < 32) STAGE(tb+3, 24576)
    TILE(0)
    TILE(8192)
    __syncthreads();
    if (tb + 4 < 32) STAGE(tb+4, 0)
    if (tb + 5 < 32) STAGE(tb+5, 8192)
    TILE(16384)
    TILE(24576)
    __syncthreads();
  }
#undef STAGE
#undef TILE

  l += __shfl_xor(l, 32);
  float inv = 1.f / l;
  int b = bh >> 4, hh = bh & 15;
  short* ob = Oh + (((size_t)(b*SS + qrow0 + lq)) << 10) + hh*64 + 4*h;
  #pragma unroll
  for (int rg=0;rg<4;++rg){
    i32x2 pk;
    pk.x = (int)cvtpk(oA[rg*4+0]*inv, oA[rg*4+1]*inv);
    pk.y = (int)cvtpk(oA[rg*4+2]*inv, oA[rg*4+3]*inv);
    *(i32x2*)(ob + 8*rg) = pk;          // d-block 0: d = 8*rg + 4*h + 0..3
    pk.x = (int)cvtpk(oB[rg*4+0]*inv, oB[rg*4+1]*inv);
    pk.y = (int)cvtpk(oB[rg*4+2]*inv, oB[rg*4+3]*inv);
    *(i32x2*)(ob + 32 + 8*rg) = pk;     // d-block 1
  }
}

extern "C" void kernel_launch(void* const* d_in, const int* in_sizes, int n_in,
                              void* d_out, int out_size, void* d_ws, size_t ws_size,
                              hipStream_t stream){
  const float* q  = (const float*)d_in[0];
  const float* k  = (const float*)d_in[1];
  const float* v  = (const float*)d_in[2];
  const float* Wq = (const float*)d_in[3];
  const float* bq = (const float*)d_in[4];
  const float* Wk = (const float*)d_in[5];
  const float* bk = (const float*)d_in[6];
  const float* Wv = (const float*)d_in[7];
  const float* bv = (const float*)d_in[8];
  const float* Wo = (const float*)d_in[9];
  const float* bo = (const float*)d_in[10];
  (void)in_sizes; (void)n_in; (void)out_size; (void)ws_size;

  short* wsp = (short*)d_ws;
  const size_t MW = 1048576;          // one 1024x1024 bf16 matrix, in elements
  short* WT3 = wsp;                   // WTq, WTk, WTv contiguous
  short* WTo = wsp + 3*MW;
  short* Qh  = wsp + 4*MW;            // [B,H,S,64] bf16 (pre-scaled by 0.125*log2e)
  short* Kh  = wsp + 8*MW;            // [B,H,S,64] bf16
  short* Oh  = wsp + 12*MW;           // attention out [B*S,1024] bf16
  short* Vt  = wsp + 16*MW;           // [B,H,64,S] bf16 (written directly by gemm)

  const float QSCALE = 0.125f * 1.44269504088896f;  // fold 1/sqrt(dk) and log2(e)
  wtrans_kernel<<<dim3(256,4), 256, 0, stream>>>(Wq, Wk, Wv, Wo, wsp);
  gemm_qkv3_kernel<<<dim3(32,8,3), 256, 0, stream>>>(q, k, v, WT3, bq, bk, bv,
                                                     Qh, Kh, Vt, QSCALE);
  attn_kernel<<<dim3(16,32), 256, 0, stream>>>(Qh, Kh, Vt, Oh);
  gemm_out_kernel<<<dim3(32,16), 256, 0, stream>>>(Oh, WTo, bo, (float*)d_out);
}

// Round 19
// 115.025 us; speedup vs baseline: 1.1233x; 1.0071x over previous
//
#include <hip/hip_runtime.h>
#include <hip/hip_bf16.h>

#define BB 2
#define SS 2048
#define HH 16
#define DD 64
#define DM 1024
#define MM (BB*SS)   // 4096

typedef __attribute__((ext_vector_type(4))) float f32x4;
typedef __attribute__((ext_vector_type(16))) float f32x16;
typedef __attribute__((ext_vector_type(8))) short s16x8;
typedef __attribute__((ext_vector_type(2))) int i32x2;

__device__ __forceinline__ unsigned short f2bf(float f){
  unsigned int u = __float_as_uint(f);
  u += 0x7FFF + ((u >> 16) & 1);   // round-to-nearest-even
  return (unsigned short)(u >> 16);
}

__device__ __forceinline__ f32x4 zero4(){ f32x4 z = {0.f,0.f,0.f,0.f}; return z; }

__device__ __forceinline__ unsigned int cvtpk(float a, float b){
  unsigned int r;
  asm("v_cvt_pk_bf16_f32 %0, %1, %2" : "=v"(r) : "v"(a), "v"(b));
  return r;
}

// async global->LDS, 16B per lane; LDS dest is wave-uniform base + lane*16
__device__ __forceinline__ void gload_lds16(const void* g, void* l){
  __builtin_amdgcn_global_load_lds(
    (const __attribute__((address_space(1))) unsigned int*)g,
    (__attribute__((address_space(3))) unsigned int*)l, 16, 0, 0);
}

// ---------------- weight transpose + f32->bf16:  WT[n][k] = W[k][n] ----------------
__global__ __launch_bounds__(256) void wtrans_kernel(
    const float* __restrict__ Wq, const float* __restrict__ Wk,
    const float* __restrict__ Wv, const float* __restrict__ Wo,
    short* __restrict__ wt){
  __shared__ float tile[64][65];
  const float* src = (blockIdx.y==0)?Wq:(blockIdx.y==1)?Wk:(blockIdx.y==2)?Wv:Wo;
  short* dst = wt + (size_t)blockIdx.y * ((size_t)DM*DM);
  int tk = (blockIdx.x >> 4) * 64;   // rows of W (k)
  int tn = (blockIdx.x & 15) * 64;   // cols of W (n)
  int t = threadIdx.x;
  int r = t >> 2;
  int c4 = (t & 3) << 4;
  const float* p = src + (size_t)(tk + r) * DM + tn + c4;
  #pragma unroll
  for (int i = 0; i < 4; ++i){
    float4 vv = *(const float4*)(p + i*4);
    tile[r][c4 + i*4 + 0] = vv.x;
    tile[r][c4 + i*4 + 1] = vv.y;
    tile[r][c4 + i*4 + 2] = vv.z;
    tile[r][c4 + i*4 + 3] = vv.w;
  }
  __syncthreads();
  s16x8 o0, o1;
  #pragma unroll
  for (int j = 0; j < 8; ++j) o0[j] = (short)f2bf(tile[c4 + j][r]);
  #pragma unroll
  for (int j = 0; j < 8; ++j) o1[j] = (short)f2bf(tile[c4 + 8 + j][r]);
  short* qd = dst + (size_t)(tn + r) * DM + tk + c4;
  *(s16x8*)qd       = o0;
  *(s16x8*)(qd + 8) = o1;
}

// ---------------- GEMM cores ---------------------------------------------------------
#define ALOAD_F32(k0_) { \
  _Pragma("unroll") for (int ch=0; ch<4; ++ch){ \
    areg[2*ch]   = *(const float4*)(Apf + (size_t)ch*32*DM + (k0_)); \
    areg[2*ch+1] = *(const float4*)(Apf + (size_t)ch*32*DM + (k0_) + 4); \
  } }

#define AWRITE(AB_) { \
  _Pragma("unroll") for (int ch=0; ch<4; ++ch){ \
    int4 pk4; \
    pk4.x = (int)cvtpk(areg[2*ch].x,   areg[2*ch].y); \
    pk4.y = (int)cvtpk(areg[2*ch].z,   areg[2*ch].w); \
    pk4.z = (int)cvtpk(areg[2*ch+1].x, areg[2*ch+1].y); \
    pk4.w = (int)cvtpk(areg[2*ch+1].z, areg[2*ch+1].w); \
    *(int4*)((char*)(AB_) + ch*4096 + adst) = pk4; \
  } }

// ----- 128-wide-B variant (qkv3, m97 128x128 tile, 4 waves) -----
#define GEMM_PRE_128() \
  int m0 = blockIdx.x * 128, n0 = blockIdx.y * 128; \
  int t = threadIdx.x; \
  int w = t >> 6, lane = t & 63, g = lane >> 4, c = lane & 15; \
  int wm = (w >> 1) * 64, wn = (w & 1) * 64; \
  f32x4 acc[4][4]; \
  _Pragma("unroll") for (int i=0;i<4;++i) \
    _Pragma("unroll") for (int j=0;j<4;++j) acc[i][j] = zero4(); \
  int srow = t >> 3; \
  int scol = ((t & 7) ^ (srow & 7)) * 8; \
  const short* Bp = BT + (size_t)(n0 + srow) * DM + scol; \
  int rsw = (c & 7) << 4; \
  int adst = srow*128 + (t & 7)*16;

#define BSTAGE128(k0_, BB_) { \
  gload_lds16(Bp + (k0_),          (char*)(BB_) + w*1024); \
  gload_lds16(Bp + 32*DM + (k0_),  (char*)(BB_) + 4096  + w*1024); \
  gload_lds16(Bp + 64*DM + (k0_),  (char*)(BB_) + 8192  + w*1024); \
  gload_lds16(Bp + 96*DM + (k0_),  (char*)(BB_) + 12288 + w*1024); \
}

#define GCOMP128(AB_, BB_) { \
  s16x8 af[4][2], bfr[4][2]; \
  _Pragma("unroll") for (int mi=0;mi<4;++mi){ \
    const char* arow = (const char*)(AB_) + (wm + mi*16 + c)*128; \
    af[mi][0] = *(const s16x8*)(arow + ((g*16) ^ rsw)); \
    af[mi][1] = *(const s16x8*)(arow + ((64 + g*16) ^ rsw)); \
  } \
  _Pragma("unroll") for (int ni=0;ni<4;++ni){ \
    const char* brow = (const char*)(BB_) + (wn + ni*16 + c)*128; \
    bfr[ni][0] = *(const s16x8*)(brow + ((g*16) ^ rsw)); \
    bfr[ni][1] = *(const s16x8*)(brow + ((64 + g*16) ^ rsw)); \
  } \
  _Pragma("unroll") for (int mi=0;mi<4;++mi) \
    _Pragma("unroll") for (int ni=0;ni<4;++ni){ \
      acc[mi][ni] = __builtin_amdgcn_mfma_f32_16x16x32_bf16(af[mi][0], bfr[ni][0], acc[mi][ni], 0,0,0); \
      acc[mi][ni] = __builtin_amdgcn_mfma_f32_16x16x32_bf16(af[mi][1], bfr[ni][1], acc[mi][ni], 0,0,0); \
    } \
}

#define GEMM_LOOP_F32_128() \
  float4 areg[8]; \
  ALOAD_F32(0) \
  BSTAGE128(0, &Bs[0][0]) \
  AWRITE(&As[0][0]) \
  __syncthreads(); \
  for (int kk = 0; kk < DM; kk += 128){ \
    if (kk + 64 < DM){ ALOAD_F32(kk+64) BSTAGE128(kk+64, &Bs[1][0]) } \
    GCOMP128(&As[0][0], &Bs[0][0]) \
    if (kk + 64 < DM){ AWRITE(&As[1][0]) } \
    __syncthreads(); \
    if (kk + 128 < DM){ ALOAD_F32(kk+128) BSTAGE128(kk+128, &Bs[0][0]) } \
    GCOMP128(&As[1][0], &Bs[1][0]) \
    if (kk + 128 < DM){ AWRITE(&As[0][0]) } \
    __syncthreads(); \
  }

// fused Q/K/V projection GEMM (128x128 tile): blockIdx.z selects slice.
// z=0: Qh (scale=qscale), z=1: Kh, z=2: Vt (transposed epilogue).
__global__ __launch_bounds__(256) void gemm_qkv3_kernel(
    const float* __restrict__ qs, const float* __restrict__ ks,
    const float* __restrict__ vs, const short* __restrict__ WT3,
    const float* __restrict__ bq, const float* __restrict__ bk,
    const float* __restrict__ bv,
    short* __restrict__ Qh, short* __restrict__ Kh, short* __restrict__ Vt,
    float qscale){
  __shared__ __align__(16) short As[2][128*64];
  __shared__ __align__(16) short Bs[2][128*64];
  int z = blockIdx.z;
  const float* A    = (z==0) ? qs : (z==1) ? ks : vs;
  const short* BT   = WT3 + (size_t)z * ((size_t)DM*DM);
  const float* bias = (z==0) ? bq : (z==1) ? bk : bv;
  GEMM_PRE_128()
  const float* Apf = A + (size_t)(m0 + srow) * DM + scol;
  GEMM_LOOP_F32_128()
  if (z < 2){
    short* outh = (z==0) ? Qh : Kh;
    float scale = (z==0) ? qscale : 1.0f;
    #pragma unroll
    for (int ni=0;ni<4;++ni){
      int col = n0 + wn + ni*16 + c;
      float bvv = bias[col];
      int hh = col >> 6, d = col & 63;
      #pragma unroll
      for (int mi=0;mi<4;++mi){
        #pragma unroll
        for (int r=0;r<4;++r){
          int row = m0 + wm + mi*16 + g*4 + r;
          int b = row >> 11, s = row & (SS-1);
          float val = (acc[mi][ni][r] + bvv) * scale;
          outh[((((size_t)b*HH + hh)*SS + s) << 6) + d] = (short)f2bf(val);
        }
      }
    }
  } else {
    #pragma unroll
    for (int ni=0;ni<4;++ni){
      int col = n0 + wn + ni*16 + c;
      float bvv = bias[col];
      int hh = col >> 6, d = col & 63;
      #pragma unroll
      for (int mi=0;mi<4;++mi){
        int row = m0 + wm + mi*16 + g*4;
        int b = row >> 11, s = row & (SS-1);
        i32x2 pk2;
        pk2.x = (int)cvtpk(acc[mi][ni][0] + bvv, acc[mi][ni][1] + bvv);
        pk2.y = (int)cvtpk(acc[mi][ni][2] + bvv, acc[mi][ni][3] + bvv);
        *(i32x2*)(Vt + (((size_t)(b*HH + hh)*64 + d) * SS + s)) = pk2;
      }
    }
  }
}

// ---------------- output GEMM: 128x128 tile, 8 waves (512 threads) ------------------
// Same swizzle invariant LDS[row][p] = global[row][p^(row&7)]; 512-thread staging:
// srow = t>>3 (0..63), chunk = t&7; two gload lines cover rows 0-63 / 64-127.
// Waves 2Mx4N: wm=(w>>2)*64, wn=(w&3)*32; acc[4][2] (16 MFMA/wave/step).
// LDS 64KB -> 2 blocks/CU; grid 256 -> all resident, 2 waves/SIMD (same as before,
// but MFMA:staged-bytes ratio 1.5x and half the barriers per output element).
__global__ __launch_bounds__(512) void gemm_out_kernel(
    const short* __restrict__ A, const short* __restrict__ BT,
    const float* __restrict__ bias, float* __restrict__ out){
  __shared__ __align__(16) short As[2][128*64];
  __shared__ __align__(16) short Bs[2][128*64];
  int m0 = blockIdx.x * 128, n0 = blockIdx.y * 128;
  int t = threadIdx.x;
  int w = t >> 6, lane = t & 63, g = lane >> 4, c = lane & 15;
  int wm = (w >> 2) * 64, wn = (w & 3) * 32;
  f32x4 acc[4][2];
  #pragma unroll
  for (int i=0;i<4;++i)
    #pragma unroll
    for (int j=0;j<2;++j) acc[i][j] = zero4();
  int srow = t >> 3;                       // 0..63
  int scol = ((t & 7) ^ (srow & 7)) * 8;   // pre-swizzled source col
  const short* Apb = A  + (size_t)(m0 + srow) * DM + scol;
  const short* Bp  = BT + (size_t)(n0 + srow) * DM + scol;
  int rsw = (c & 7) << 4;

#define OSTAGE_A(k0_, AB_) { \
    gload_lds16(Apb + (k0_),         (char*)(AB_) + w*1024); \
    gload_lds16(Apb + 64*DM + (k0_), (char*)(AB_) + 8192 + w*1024); \
  }
#define OSTAGE_B(k0_, BB_) { \
    gload_lds16(Bp + (k0_),          (char*)(BB_) + w*1024); \
    gload_lds16(Bp + 64*DM + (k0_),  (char*)(BB_) + 8192 + w*1024); \
  }
#define OCOMP(AB_, BB_) { \
    s16x8 af[4][2], bfr[2][2]; \
    _Pragma("unroll") for (int mi=0;mi<4;++mi){ \
      const char* arow = (const char*)(AB_) + (wm + mi*16 + c)*128; \
      af[mi][0] = *(const s16x8*)(arow + ((g*16) ^ rsw)); \
      af[mi][1] = *(const s16x8*)(arow + ((64 + g*16) ^ rsw)); \
    } \
    _Pragma("unroll") for (int ni=0;ni<2;++ni){ \
      const char* brow = (const char*)(BB_) + (wn + ni*16 + c)*128; \
      bfr[ni][0] = *(const s16x8*)(brow + ((g*16) ^ rsw)); \
      bfr[ni][1] = *(const s16x8*)(brow + ((64 + g*16) ^ rsw)); \
    } \
    _Pragma("unroll") for (int mi=0;mi<4;++mi) \
      _Pragma("unroll") for (int ni=0;ni<2;++ni){ \
        acc[mi][ni] = __builtin_amdgcn_mfma_f32_16x16x32_bf16(af[mi][0], bfr[ni][0], acc[mi][ni], 0,0,0); \
        acc[mi][ni] = __builtin_amdgcn_mfma_f32_16x16x32_bf16(af[mi][1], bfr[ni][1], acc[mi][ni], 0,0,0); \
      } \
  }

  OSTAGE_A(0, &As[0][0])
  OSTAGE_B(0, &Bs[0][0])
  __syncthreads();
  for (int kk = 0; kk < DM; kk += 128){
    if (kk + 64 < DM){ OSTAGE_A(kk+64, &As[1][0]) OSTAGE_B(kk+64, &Bs[1][0]) }
    OCOMP(&As[0][0], &Bs[0][0])
    __syncthreads();
    if (kk + 128 < DM){ OSTAGE_A(kk+128, &As[0][0]) OSTAGE_B(kk+128, &Bs[0][0]) }
    OCOMP(&As[1][0], &Bs[1][0])
    __syncthreads();
  }
#undef OSTAGE_A
#undef OSTAGE_B
#undef OCOMP

  #pragma unroll
  for (int ni=0;ni<2;++ni){
    int col = n0 + wn + ni*16 + c;
    float bvv = bias[col];
    #pragma unroll
    for (int mi=0;mi<4;++mi){
      #pragma unroll
      for (int r=0;r<4;++r){
        int row = m0 + wm + mi*16 + g*4 + r;
        out[(size_t)row * DM + col] = acc[mi][ni][r] + bvv;
      }
    }
  }
}

// ---------------- flash attention: 32x32 MFMA, quad-buffered, XCD remap -------------
// (R18 version, best safe attn)
__global__ __launch_bounds__(256) void attn_kernel(
    const short* __restrict__ Qh, const short* __restrict__ Kh,
    const short* __restrict__ Vt, short* __restrict__ Oh){
  __shared__ __align__(16) short SMEM[32768];      // 64 KB
  int n = blockIdx.x + (blockIdx.y << 4);
  int bh = (n & 7) | ((n >> 7) << 3);
  int qb = ((n >> 3) & 15) * 128;
  int t = threadIdx.x, w = t >> 6, lane = t & 63;
  int lq = lane & 31, h = lane >> 5;
  int qrow0 = qb + w*32;

  const short* qg = Qh + (((size_t)bh*SS + qrow0 + lq) << 6) + h*8;
  s16x8 qf[4];
  #pragma unroll
  for (int kc=0;kc<4;++kc) qf[kc] = *(const s16x8*)(qg + kc*16);

  f32x16 z16;
  #pragma unroll
  for (int i=0;i<16;++i) z16[i] = 0.f;
  f32x16 oA, oB;
  #pragma unroll
  for (int i=0;i<16;++i){ oA[i]=0.f; oB[i]=0.f; }
  float l = 0.f;
  const char* kbase = (const char*)(Kh + (((size_t)bh*SS) << 6));
  const char* vbase = (const char*)(Vt + ((size_t)bh*64) * SS);

  int rsel = lane >> 3;
  int csw  = ((lane & 7) << 4) ^ (rsel << 4);
  int swr  = (lane & 7) << 4;

  const char* smem = (const char*)&SMEM[0];
  const char* kr0 = smem + lq*128 + (( 0 + h*16) ^ swr);
  const char* kr1 = smem + lq*128 + ((32 + h*16) ^ swr);
  const char* kr2 = smem + lq*128 + ((64 + h*16) ^ swr);
  const char* kr3 = smem + lq*128 + ((96 + h*16) ^ swr);
  char* smem_w = (char*)&SMEM[0] + w*2048;

#define STAGE(T, KOFF) { \
    const char* kg = kbase + (((size_t)((T)*64 + w*16 + rsel)) << 7) + csw; \
    gload_lds16(kg,        smem_w + (KOFF)); \
    gload_lds16(kg + 1024, smem_w + (KOFF) + 1024); \
    const char* vg = vbase + (size_t)(w*16 + rsel) * (SS*2) + ((size_t)(T) << 7) + csw; \
    gload_lds16(vg,            smem_w + (KOFF) + 32768); \
    gload_lds16(vg + 8*(SS*2), smem_w + (KOFF) + 32768 + 1024); \
  }

#define MFMA32(a_, b_, c_) __builtin_amdgcn_mfma_f32_32x32x16_bf16(a_, b_, c_, 0,0,0)

#define TILE(KOFF) { \
    f32x16 sA, sB; \
    s16x8 kf; \
    __builtin_amdgcn_s_setprio(1); \
    kf = *(const s16x8*)(kr0 + (KOFF));        sA = MFMA32(kf, qf[0], z16); \
    kf = *(const s16x8*)(kr0 + (KOFF) + 4096); sB = MFMA32(kf, qf[0], z16); \
    kf = *(const s16x8*)(kr1 + (KOFF));        sA = MFMA32(kf, qf[1], sA); \
    kf = *(const s16x8*)(kr1 + (KOFF) + 4096); sB = MFMA32(kf, qf[1], sB); \
    kf = *(const s16x8*)(kr2 + (KOFF));        sA = MFMA32(kf, qf[2], sA); \
    kf = *(const s16x8*)(kr2 + (KOFF) + 4096); sB = MFMA32(kf, qf[2], sB); \
    kf = *(const s16x8*)(kr3 + (KOFF));        sA = MFMA32(kf, qf[3], sA); \
    kf = *(const s16x8*)(kr3 + (KOFF) + 4096); sB = MFMA32(kf, qf[3], sB); \
    __builtin_amdgcn_s_setprio(0); \
    float lp = 0.f; \
    unsigned int cA[8], cB[8]; \
    _Pragma("unroll") \
    for (int i=0;i<8;++i){ \
      float a0 = __builtin_amdgcn_exp2f(sA[2*i]); \
      float a1 = __builtin_amdgcn_exp2f(sA[2*i+1]); \
      float b0 = __builtin_amdgcn_exp2f(sB[2*i]); \
      float b1 = __builtin_amdgcn_exp2f(sB[2*i+1]); \
      lp += (a0 + a1) + (b0 + b1); \
      cA[i] = cvtpk(a0, a1); \
      cB[i] = cvtpk(b0, b1); \
    } \
    l += lp; \
    asm("v_permlane32_swap_b32 %0, %1" : "+v"(cA[0]), "+v"(cA[2])); \
    asm("v_permlane32_swap_b32 %0, %1" : "+v"(cA[1]), "+v"(cA[3])); \
    asm("v_permlane32_swap_b32 %0, %1" : "+v"(cA[4]), "+v"(cA[6])); \
    asm("v_permlane32_swap_b32 %0, %1" : "+v"(cA[5]), "+v"(cA[7])); \
    asm("v_permlane32_swap_b32 %0, %1" : "+v"(cB[0]), "+v"(cB[2])); \
    asm("v_permlane32_swap_b32 %0, %1" : "+v"(cB[1]), "+v"(cB[3])); \
    asm("v_permlane32_swap_b32 %0, %1" : "+v"(cB[4]), "+v"(cB[6])); \
    asm("v_permlane32_swap_b32 %0, %1" : "+v"(cB[5]), "+v"(cB[7])); \
    s16x8 pbf0, pbf1, pbf2, pbf3; \
    { unsigned int* p0 = (unsigned int*)&pbf0; \
      p0[0]=cA[0]; p0[1]=cA[1]; p0[2]=cA[2]; p0[3]=cA[3]; \
      unsigned int* p1 = (unsigned int*)&pbf1; \
      p1[0]=cA[4]; p1[1]=cA[5]; p1[2]=cA[6]; p1[3]=cA[7]; \
      unsigned int* p2 = (unsigned int*)&pbf2; \
      p2[0]=cB[0]; p2[1]=cB[1]; p2[2]=cB[2]; p2[3]=cB[3]; \
      unsigned int* p3 = (unsigned int*)&pbf3; \
      p3[0]=cB[4]; p3[1]=cB[5]; p3[2]=cB[6]; p3[3]=cB[7]; } \
    __builtin_amdgcn_s_setprio(1); \
    kf = *(const s16x8*)(kr0 + (KOFF) + 32768);        oA = MFMA32(kf, pbf0, oA); \
    kf = *(const s16x8*)(kr0 + (KOFF) + 32768 + 4096); oB = MFMA32(kf, pbf0, oB); \
    kf = *(const s16x8*)(kr1 + (KOFF) + 32768);        oA = MFMA32(kf, pbf1, oA); \
    kf = *(const s16x8*)(kr1 + (KOFF) + 32768 + 4096); oB = MFMA32(kf, pbf1, oB); \
    kf = *(const s16x8*)(kr2 + (KOFF) + 32768);        oA = MFMA32(kf, pbf2, oA); \
    kf = *(const s16x8*)(kr2 + (KOFF) + 32768 + 4096); oB = MFMA32(kf, pbf2, oB); \
    kf = *(const s16x8*)(kr3 + (KOFF) + 32768);        oA = MFMA32(kf, pbf3, oA); \
    kf = *(const s16x8*)(kr3 + (KOFF) + 32768 + 4096); oB = MFMA32(kf, pbf3, oB); \
    __builtin_amdgcn_s_setprio(0); \
  }

  // prologue: tiles 0,1 into bufs 0,1
  STAGE(0, 0)
  STAGE(1, 8192)
  __syncthreads();

  for (int tb = 0; tb < 32; tb += 4){
    if (tb + 2 < 32) STAGE(tb+2, 16384)
    if (tb + 3 < 32) STAGE(tb+3, 24576)
    TILE(0)
    TILE(8192)
    __syncthreads();
    if (tb + 4 < 32) STAGE(tb+4, 0)
    if (tb + 5 < 32) STAGE(tb+5, 8192)
    TILE(16384)
    TILE(24576)
    __syncthreads();
  }
#undef STAGE
#undef TILE

  l += __shfl_xor(l, 32);
  float inv = 1.f / l;
  int b = bh >> 4, hh = bh & 15;
  short* ob = Oh + (((size_t)(b*SS + qrow0 + lq)) << 10) + hh*64 + 4*h;
  #pragma unroll
  for (int rg=0;rg<4;++rg){
    i32x2 pk;
    pk.x = (int)cvtpk(oA[rg*4+0]*inv, oA[rg*4+1]*inv);
    pk.y = (int)cvtpk(oA[rg*4+2]*inv, oA[rg*4+3]*inv);
    *(i32x2*)(ob + 8*rg) = pk;          // d-block 0: d = 8*rg + 4*h + 0..3
    pk.x = (int)cvtpk(oB[rg*4+0]*inv, oB[rg*4+1]*inv);
    pk.y = (int)cvtpk(oB[rg*4+2]*inv, oB[rg*4+3]*inv);
    *(i32x2*)(ob + 32 + 8*rg) = pk;     // d-block 1
  }
}

extern "C" void kernel_launch(void* const* d_in, const int* in_sizes, int n_in,
                              void* d_out, int out_size, void* d_ws, size_t ws_size,
                              hipStream_t stream){
  const float* q  = (const float*)d_in[0];
  const float* k  = (const float*)d_in[1];
  const float* v  = (const float*)d_in[2];
  const float* Wq = (const float*)d_in[3];
  const float* bq = (const float*)d_in[4];
  const float* Wk = (const float*)d_in[5];
  const float* bk = (const float*)d_in[6];
  const float* Wv = (const float*)d_in[7];
  const float* bv = (const float*)d_in[8];
  const float* Wo = (const float*)d_in[9];
  const float* bo = (const float*)d_in[10];
  (void)in_sizes; (void)n_in; (void)out_size; (void)ws_size;

  short* wsp = (short*)d_ws;
  const size_t MW = 1048576;          // one 1024x1024 bf16 matrix, in elements
  short* WT3 = wsp;                   // WTq, WTk, WTv contiguous
  short* WTo = wsp + 3*MW;
  short* Qh  = wsp + 4*MW;            // [B,H,S,64] bf16 (pre-scaled by 0.125*log2e)
  short* Kh  = wsp + 8*MW;            // [B,H,S,64] bf16
  short* Oh  = wsp + 12*MW;           // attention out [B*S,1024] bf16
  short* Vt  = wsp + 16*MW;           // [B,H,64,S] bf16 (written directly by gemm)

  const float QSCALE = 0.125f * 1.44269504088896f;  // fold 1/sqrt(dk) and log2(e)
  wtrans_kernel<<<dim3(256,4), 256, 0, stream>>>(Wq, Wk, Wv, Wo, wsp);
  gemm_qkv3_kernel<<<dim3(32,8,3), 256, 0, stream>>>(q, k, v, WT3, bq, bk, bv,
                                                     Qh, Kh, Vt, QSCALE);
  attn_kernel<<<dim3(16,32), 256, 0, stream>>>(Qh, Kh, Vt, Oh);
  gemm_out_kernel<<<dim3(32,8), 512, 0, stream>>>(Oh, WTo, bo, (float*)d_out);
}

// Round 20
// 108.436 us; speedup vs baseline: 1.1916x; 1.0608x over previous
//
#include <hip/hip_runtime.h>
#include <hip/hip_bf16.h>

#define BB 2
#define SS 2048
#define HH 16
#define DD 64
#define DM 1024
#define MM (BB*SS)   // 4096

typedef __attribute__((ext_vector_type(4))) float f32x4;
typedef __attribute__((ext_vector_type(16))) float f32x16;
typedef __attribute__((ext_vector_type(8))) short s16x8;
typedef __attribute__((ext_vector_type(2))) int i32x2;

__device__ __forceinline__ unsigned short f2bf(float f){
  unsigned int u = __float_as_uint(f);
  u += 0x7FFF + ((u >> 16) & 1);   // round-to-nearest-even
  return (unsigned short)(u >> 16);
}

__device__ __forceinline__ f32x4 zero4(){ f32x4 z = {0.f,0.f,0.f,0.f}; return z; }

__device__ __forceinline__ unsigned int cvtpk(float a, float b){
  unsigned int r;
  asm("v_cvt_pk_bf16_f32 %0, %1, %2" : "=v"(r) : "v"(a), "v"(b));
  return r;
}

// async global->LDS, 16B per lane; LDS dest is wave-uniform base + lane*16
__device__ __forceinline__ void gload_lds16(const void* g, void* l){
  __builtin_amdgcn_global_load_lds(
    (const __attribute__((address_space(1))) unsigned int*)g,
    (__attribute__((address_space(3))) unsigned int*)l, 16, 0, 0);
}

// ---------------- weight transpose + f32->bf16:  WT[n][k] = W[k][n] ----------------
__global__ __launch_bounds__(256) void wtrans_kernel(
    const float* __restrict__ Wq, const float* __restrict__ Wk,
    const float* __restrict__ Wv, const float* __restrict__ Wo,
    short* __restrict__ wt){
  __shared__ float tile[64][65];
  const float* src = (blockIdx.y==0)?Wq:(blockIdx.y==1)?Wk:(blockIdx.y==2)?Wv:Wo;
  short* dst = wt + (size_t)blockIdx.y * ((size_t)DM*DM);
  int tk = (blockIdx.x >> 4) * 64;   // rows of W (k)
  int tn = (blockIdx.x & 15) * 64;   // cols of W (n)
  int t = threadIdx.x;
  int r = t >> 2;
  int c4 = (t & 3) << 4;
  const float* p = src + (size_t)(tk + r) * DM + tn + c4;
  #pragma unroll
  for (int i = 0; i < 4; ++i){
    float4 vv = *(const float4*)(p + i*4);
    tile[r][c4 + i*4 + 0] = vv.x;
    tile[r][c4 + i*4 + 1] = vv.y;
    tile[r][c4 + i*4 + 2] = vv.z;
    tile[r][c4 + i*4 + 3] = vv.w;
  }
  __syncthreads();
  s16x8 o0, o1;
  #pragma unroll
  for (int j = 0; j < 8; ++j) o0[j] = (short)f2bf(tile[c4 + j][r]);
  #pragma unroll
  for (int j = 0; j < 8; ++j) o1[j] = (short)f2bf(tile[c4 + 8 + j][r]);
  short* qd = dst + (size_t)(tn + r) * DM + tk + c4;
  *(s16x8*)qd       = o0;
  *(s16x8*)(qd + 8) = o1;
}

// ---------------- fused Q/K/V projection GEMM: 128x128 tile, 8 waves ----------------
// 512 threads, waves 2Mx4N (wm=(w>>2)*64, wn=(w&3)*32), acc[4][2] per wave.
// Swizzle invariant LDS[row][chunk] = global[row][chunk ^ (row&7)] (16B chunks).
// B: gload_lds direct (bf16 weights); A: f32 reg-staged (load pre-swizzled source
// chunk, cvt_pk, ds_write_b128 to linear dest chunk). All-drain-barrier dbuf loop.
// LDS 64KB -> 2 blocks/CU = 16 waves/CU = 4 waves/SIMD.
__global__ __launch_bounds__(512) void gemm_qkv3_kernel(
    const float* __restrict__ qs, const float* __restrict__ ks,
    const float* __restrict__ vs, const short* __restrict__ WT3,
    const float* __restrict__ bq, const float* __restrict__ bk,
    const float* __restrict__ bv,
    short* __restrict__ Qh, short* __restrict__ Kh, short* __restrict__ Vt,
    float qscale){
  __shared__ __align__(16) short As[2][128*64];
  __shared__ __align__(16) short Bs[2][128*64];
  int z = blockIdx.z;
  const float* A    = (z==0) ? qs : (z==1) ? ks : vs;
  const short* BT   = WT3 + (size_t)z * ((size_t)DM*DM);
  const float* bias = (z==0) ? bq : (z==1) ? bk : bv;
  int m0 = blockIdx.x * 128, n0 = blockIdx.y * 128;
  int t = threadIdx.x;
  int w = t >> 6, lane = t & 63, g = lane >> 4, c = lane & 15;
  int wm = (w >> 2) * 64, wn = (w & 3) * 32;
  f32x4 acc[4][2];
  #pragma unroll
  for (int i=0;i<4;++i)
    #pragma unroll
    for (int j=0;j<2;++j) acc[i][j] = zero4();
  int srow = t >> 3;                       // 0..63
  int scol = ((t & 7) ^ (srow & 7)) * 8;   // pre-swizzled source col (elements)
  const short* Bp  = BT + (size_t)(n0 + srow) * DM + scol;
  const float* Apf = A  + (size_t)(m0 + srow) * DM + scol;
  int rsw = (c & 7) << 4;
  int adst = srow*128 + (t & 7)*16;        // linear dest chunk

#define QSTAGE_B(k0_, BB_) { \
    gload_lds16(Bp + (k0_),          (char*)(BB_) + w*1024); \
    gload_lds16(Bp + 64*DM + (k0_),  (char*)(BB_) + 8192 + w*1024); \
  }
#define QLOAD_A(k0_) { \
    areg[0] = *(const float4*)(Apf + (k0_)); \
    areg[1] = *(const float4*)(Apf + (k0_) + 4); \
    areg[2] = *(const float4*)(Apf + 64*DM + (k0_)); \
    areg[3] = *(const float4*)(Apf + 64*DM + (k0_) + 4); \
  }
#define QWRITE_A(AB_) { \
    int4 pk0, pk1; \
    pk0.x = (int)cvtpk(areg[0].x, areg[0].y); \
    pk0.y = (int)cvtpk(areg[0].z, areg[0].w); \
    pk0.z = (int)cvtpk(areg[1].x, areg[1].y); \
    pk0.w = (int)cvtpk(areg[1].z, areg[1].w); \
    pk1.x = (int)cvtpk(areg[2].x, areg[2].y); \
    pk1.y = (int)cvtpk(areg[2].z, areg[2].w); \
    pk1.z = (int)cvtpk(areg[3].x, areg[3].y); \
    pk1.w = (int)cvtpk(areg[3].z, areg[3].w); \
    *(int4*)((char*)(AB_) + adst)        = pk0; \
    *(int4*)((char*)(AB_) + 8192 + adst) = pk1; \
  }
#define QCOMP(AB_, BB_) { \
    s16x8 af[4][2], bfr[2][2]; \
    _Pragma("unroll") for (int mi=0;mi<4;++mi){ \
      const char* arow = (const char*)(AB_) + (wm + mi*16 + c)*128; \
      af[mi][0] = *(const s16x8*)(arow + ((g*16) ^ rsw)); \
      af[mi][1] = *(const s16x8*)(arow + ((64 + g*16) ^ rsw)); \
    } \
    _Pragma("unroll") for (int ni=0;ni<2;++ni){ \
      const char* brow = (const char*)(BB_) + (wn + ni*16 + c)*128; \
      bfr[ni][0] = *(const s16x8*)(brow + ((g*16) ^ rsw)); \
      bfr[ni][1] = *(const s16x8*)(brow + ((64 + g*16) ^ rsw)); \
    } \
    _Pragma("unroll") for (int mi=0;mi<4;++mi) \
      _Pragma("unroll") for (int ni=0;ni<2;++ni){ \
        acc[mi][ni] = __builtin_amdgcn_mfma_f32_16x16x32_bf16(af[mi][0], bfr[ni][0], acc[mi][ni], 0,0,0); \
        acc[mi][ni] = __builtin_amdgcn_mfma_f32_16x16x32_bf16(af[mi][1], bfr[ni][1], acc[mi][ni], 0,0,0); \
      } \
  }

  float4 areg[4];
  QLOAD_A(0)
  QSTAGE_B(0, &Bs[0][0])
  QWRITE_A(&As[0][0])
  __syncthreads();
  for (int kk = 0; kk < DM; kk += 128){
    if (kk + 64 < DM){ QLOAD_A(kk+64) QSTAGE_B(kk+64, &Bs[1][0]) }
    QCOMP(&As[0][0], &Bs[0][0])
    if (kk + 64 < DM){ QWRITE_A(&As[1][0]) }
    __syncthreads();
    if (kk + 128 < DM){ QLOAD_A(kk+128) QSTAGE_B(kk+128, &Bs[0][0]) }
    QCOMP(&As[1][0], &Bs[1][0])
    if (kk + 128 < DM){ QWRITE_A(&As[0][0]) }
    __syncthreads();
  }
#undef QSTAGE_B
#undef QLOAD_A
#undef QWRITE_A
#undef QCOMP

  if (z < 2){
    short* outh = (z==0) ? Qh : Kh;
    float scale = (z==0) ? qscale : 1.0f;
    #pragma unroll
    for (int ni=0;ni<2;++ni){
      int col = n0 + wn + ni*16 + c;
      float bvv = bias[col];
      int hh = col >> 6, d = col & 63;
      #pragma unroll
      for (int mi=0;mi<4;++mi){
        #pragma unroll
        for (int r=0;r<4;++r){
          int row = m0 + wm + mi*16 + g*4 + r;
          int b = row >> 11, s = row & (SS-1);
          float val = (acc[mi][ni][r] + bvv) * scale;
          outh[((((size_t)b*HH + hh)*SS + s) << 6) + d] = (short)f2bf(val);
        }
      }
    }
  } else {
    #pragma unroll
    for (int ni=0;ni<2;++ni){
      int col = n0 + wn + ni*16 + c;
      float bvv = bias[col];
      int hh = col >> 6, d = col & 63;
      #pragma unroll
      for (int mi=0;mi<4;++mi){
        int row = m0 + wm + mi*16 + g*4;
        int b = row >> 11, s = row & (SS-1);
        i32x2 pk2;
        pk2.x = (int)cvtpk(acc[mi][ni][0] + bvv, acc[mi][ni][1] + bvv);
        pk2.y = (int)cvtpk(acc[mi][ni][2] + bvv, acc[mi][ni][3] + bvv);
        *(i32x2*)(Vt + (((size_t)(b*HH + hh)*64 + d) * SS + s)) = pk2;
      }
    }
  }
}

// ---------------- output GEMM: 128x128 tile, 8 waves (512 threads) ------------------
__global__ __launch_bounds__(512) void gemm_out_kernel(
    const short* __restrict__ A, const short* __restrict__ BT,
    const float* __restrict__ bias, float* __restrict__ out){
  __shared__ __align__(16) short As[2][128*64];
  __shared__ __align__(16) short Bs[2][128*64];
  int m0 = blockIdx.x * 128, n0 = blockIdx.y * 128;
  int t = threadIdx.x;
  int w = t >> 6, lane = t & 63, g = lane >> 4, c = lane & 15;
  int wm = (w >> 2) * 64, wn = (w & 3) * 32;
  f32x4 acc[4][2];
  #pragma unroll
  for (int i=0;i<4;++i)
    #pragma unroll
    for (int j=0;j<2;++j) acc[i][j] = zero4();
  int srow = t >> 3;                       // 0..63
  int scol = ((t & 7) ^ (srow & 7)) * 8;   // pre-swizzled source col
  const short* Apb = A  + (size_t)(m0 + srow) * DM + scol;
  const short* Bp  = BT + (size_t)(n0 + srow) * DM + scol;
  int rsw = (c & 7) << 4;

#define OSTAGE_A(k0_, AB_) { \
    gload_lds16(Apb + (k0_),         (char*)(AB_) + w*1024); \
    gload_lds16(Apb + 64*DM + (k0_), (char*)(AB_) + 8192 + w*1024); \
  }
#define OSTAGE_B(k0_, BB_) { \
    gload_lds16(Bp + (k0_),          (char*)(BB_) + w*1024); \
    gload_lds16(Bp + 64*DM + (k0_),  (char*)(BB_) + 8192 + w*1024); \
  }
#define OCOMP(AB_, BB_) { \
    s16x8 af[4][2], bfr[2][2]; \
    _Pragma("unroll") for (int mi=0;mi<4;++mi){ \
      const char* arow = (const char*)(AB_) + (wm + mi*16 + c)*128; \
      af[mi][0] = *(const s16x8*)(arow + ((g*16) ^ rsw)); \
      af[mi][1] = *(const s16x8*)(arow + ((64 + g*16) ^ rsw)); \
    } \
    _Pragma("unroll") for (int ni=0;ni<2;++ni){ \
      const char* brow = (const char*)(BB_) + (wn + ni*16 + c)*128; \
      bfr[ni][0] = *(const s16x8*)(brow + ((g*16) ^ rsw)); \
      bfr[ni][1] = *(const s16x8*)(brow + ((64 + g*16) ^ rsw)); \
    } \
    _Pragma("unroll") for (int mi=0;mi<4;++mi) \
      _Pragma("unroll") for (int ni=0;ni<2;++ni){ \
        acc[mi][ni] = __builtin_amdgcn_mfma_f32_16x16x32_bf16(af[mi][0], bfr[ni][0], acc[mi][ni], 0,0,0); \
        acc[mi][ni] = __builtin_amdgcn_mfma_f32_16x16x32_bf16(af[mi][1], bfr[ni][1], acc[mi][ni], 0,0,0); \
      } \
  }

  OSTAGE_A(0, &As[0][0])
  OSTAGE_B(0, &Bs[0][0])
  __syncthreads();
  for (int kk = 0; kk < DM; kk += 128){
    if (kk + 64 < DM){ OSTAGE_A(kk+64, &As[1][0]) OSTAGE_B(kk+64, &Bs[1][0]) }
    OCOMP(&As[0][0], &Bs[0][0])
    __syncthreads();
    if (kk + 128 < DM){ OSTAGE_A(kk+128, &As[0][0]) OSTAGE_B(kk+128, &Bs[0][0]) }
    OCOMP(&As[1][0], &Bs[1][0])
    __syncthreads();
  }
#undef OSTAGE_A
#undef OSTAGE_B
#undef OCOMP

  #pragma unroll
  for (int ni=0;ni<2;++ni){
    int col = n0 + wn + ni*16 + c;
    float bvv = bias[col];
    #pragma unroll
    for (int mi=0;mi<4;++mi){
      #pragma unroll
      for (int r=0;r<4;++r){
        int row = m0 + wm + mi*16 + g*4 + r;
        out[(size_t)row * DM + col] = acc[mi][ni][r] + bvv;
      }
    }
  }
}

// ---------------- flash attention: 32x32 MFMA, quad-buffered, XCD remap -------------
// (R18 version, best safe attn)
__global__ __launch_bounds__(256) void attn_kernel(
    const short* __restrict__ Qh, const short* __restrict__ Kh,
    const short* __restrict__ Vt, short* __restrict__ Oh){
  __shared__ __align__(16) short SMEM[32768];      // 64 KB
  int n = blockIdx.x + (blockIdx.y << 4);
  int bh = (n & 7) | ((n >> 7) << 3);
  int qb = ((n >> 3) & 15) * 128;
  int t = threadIdx.x, w = t >> 6, lane = t & 63;
  int lq = lane & 31, h = lane >> 5;
  int qrow0 = qb + w*32;

  const short* qg = Qh + (((size_t)bh*SS + qrow0 + lq) << 6) + h*8;
  s16x8 qf[4];
  #pragma unroll
  for (int kc=0;kc<4;++kc) qf[kc] = *(const s16x8*)(qg + kc*16);

  f32x16 z16;
  #pragma unroll
  for (int i=0;i<16;++i) z16[i] = 0.f;
  f32x16 oA, oB;
  #pragma unroll
  for (int i=0;i<16;++i){ oA[i]=0.f; oB[i]=0.f; }
  float l = 0.f;
  const char* kbase = (const char*)(Kh + (((size_t)bh*SS) << 6));
  const char* vbase = (const char*)(Vt + ((size_t)bh*64) * SS);

  int rsel = lane >> 3;
  int csw  = ((lane & 7) << 4) ^ (rsel << 4);
  int swr  = (lane & 7) << 4;

  const char* smem = (const char*)&SMEM[0];
  const char* kr0 = smem + lq*128 + (( 0 + h*16) ^ swr);
  const char* kr1 = smem + lq*128 + ((32 + h*16) ^ swr);
  const char* kr2 = smem + lq*128 + ((64 + h*16) ^ swr);
  const char* kr3 = smem + lq*128 + ((96 + h*16) ^ swr);
  char* smem_w = (char*)&SMEM[0] + w*2048;

#define STAGE(T, KOFF) { \
    const char* kg = kbase + (((size_t)((T)*64 + w*16 + rsel)) << 7) + csw; \
    gload_lds16(kg,        smem_w + (KOFF)); \
    gload_lds16(kg + 1024, smem_w + (KOFF) + 1024); \
    const char* vg = vbase + (size_t)(w*16 + rsel) * (SS*2) + ((size_t)(T) << 7) + csw; \
    gload_lds16(vg,            smem_w + (KOFF) + 32768); \
    gload_lds16(vg + 8*(SS*2), smem_w + (KOFF) + 32768 + 1024); \
  }

#define MFMA32(a_, b_, c_) __builtin_amdgcn_mfma_f32_32x32x16_bf16(a_, b_, c_, 0,0,0)

#define TILE(KOFF) { \
    f32x16 sA, sB; \
    s16x8 kf; \
    __builtin_amdgcn_s_setprio(1); \
    kf = *(const s16x8*)(kr0 + (KOFF));        sA = MFMA32(kf, qf[0], z16); \
    kf = *(const s16x8*)(kr0 + (KOFF) + 4096); sB = MFMA32(kf, qf[0], z16); \
    kf = *(const s16x8*)(kr1 + (KOFF));        sA = MFMA32(kf, qf[1], sA); \
    kf = *(const s16x8*)(kr1 + (KOFF) + 4096); sB = MFMA32(kf, qf[1], sB); \
    kf = *(const s16x8*)(kr2 + (KOFF));        sA = MFMA32(kf, qf[2], sA); \
    kf = *(const s16x8*)(kr2 + (KOFF) + 4096); sB = MFMA32(kf, qf[2], sB); \
    kf = *(const s16x8*)(kr3 + (KOFF));        sA = MFMA32(kf, qf[3], sA); \
    kf = *(const s16x8*)(kr3 + (KOFF) + 4096); sB = MFMA32(kf, qf[3], sB); \
    __builtin_amdgcn_s_setprio(0); \
    float lp = 0.f; \
    unsigned int cA[8], cB[8]; \
    _Pragma("unroll") \
    for (int i=0;i<8;++i){ \
      float a0 = __builtin_amdgcn_exp2f(sA[2*i]); \
      float a1 = __builtin_amdgcn_exp2f(sA[2*i+1]); \
      float b0 = __builtin_amdgcn_exp2f(sB[2*i]); \
      float b1 = __builtin_amdgcn_exp2f(sB[2*i+1]); \
      lp += (a0 + a1) + (b0 + b1); \
      cA[i] = cvtpk(a0, a1); \
      cB[i] = cvtpk(b0, b1); \
    } \
    l += lp; \
    asm("v_permlane32_swap_b32 %0, %1" : "+v"(cA[0]), "+v"(cA[2])); \
    asm("v_permlane32_swap_b32 %0, %1" : "+v"(cA[1]), "+v"(cA[3])); \
    asm("v_permlane32_swap_b32 %0, %1" : "+v"(cA[4]), "+v"(cA[6])); \
    asm("v_permlane32_swap_b32 %0, %1" : "+v"(cA[5]), "+v"(cA[7])); \
    asm("v_permlane32_swap_b32 %0, %1" : "+v"(cB[0]), "+v"(cB[2])); \
    asm("v_permlane32_swap_b32 %0, %1" : "+v"(cB[1]), "+v"(cB[3])); \
    asm("v_permlane32_swap_b32 %0, %1" : "+v"(cB[4]), "+v"(cB[6])); \
    asm("v_permlane32_swap_b32 %0, %1" : "+v"(cB[5]), "+v"(cB[7])); \
    s16x8 pbf0, pbf1, pbf2, pbf3; \
    { unsigned int* p0 = (unsigned int*)&pbf0; \
      p0[0]=cA[0]; p0[1]=cA[1]; p0[2]=cA[2]; p0[3]=cA[3]; \
      unsigned int* p1 = (unsigned int*)&pbf1; \
      p1[0]=cA[4]; p1[1]=cA[5]; p1[2]=cA[6]; p1[3]=cA[7]; \
      unsigned int* p2 = (unsigned int*)&pbf2; \
      p2[0]=cB[0]; p2[1]=cB[1]; p2[2]=cB[2]; p2[3]=cB[3]; \
      unsigned int* p3 = (unsigned int*)&pbf3; \
      p3[0]=cB[4]; p3[1]=cB[5]; p3[2]=cB[6]; p3[3]=cB[7]; } \
    __builtin_amdgcn_s_setprio(1); \
    kf = *(const s16x8*)(kr0 + (KOFF) + 32768);        oA = MFMA32(kf, pbf0, oA); \
    kf = *(const s16x8*)(kr0 + (KOFF) + 32768 + 4096); oB = MFMA32(kf, pbf0, oB); \
    kf = *(const s16x8*)(kr1 + (KOFF) + 32768);        oA = MFMA32(kf, pbf1, oA); \
    kf = *(const s16x8*)(kr1 + (KOFF) + 32768 + 4096); oB = MFMA32(kf, pbf1, oB); \
    kf = *(const s16x8*)(kr2 + (KOFF) + 32768);        oA = MFMA32(kf, pbf2, oA); \
    kf = *(const s16x8*)(kr2 + (KOFF) + 32768 + 4096); oB = MFMA32(kf, pbf2, oB); \
    kf = *(const s16x8*)(kr3 + (KOFF) + 32768);        oA = MFMA32(kf, pbf3, oA); \
    kf = *(const s16x8*)(kr3 + (KOFF) + 32768 + 4096); oB = MFMA32(kf, pbf3, oB); \
    __builtin_amdgcn_s_setprio(0); \
  }

  // prologue: tiles 0,1 into bufs 0,1
  STAGE(0, 0)
  STAGE(1, 8192)
  __syncthreads();

  for (int tb = 0; tb < 32; tb += 4){
    if (tb + 2 < 32) STAGE(tb+2, 16384)
    if (tb + 3 < 32) STAGE(tb+3, 24576)
    TILE(0)
    TILE(8192)
    __syncthreads();
    if (tb + 4 < 32) STAGE(tb+4, 0)
    if (tb + 5 < 32) STAGE(tb+5, 8192)
    TILE(16384)
    TILE(24576)
    __syncthreads();
  }
#undef STAGE
#undef TILE

  l += __shfl_xor(l, 32);
  float inv = 1.f / l;
  int b = bh >> 4, hh = bh & 15;
  short* ob = Oh + (((size_t)(b*SS + qrow0 + lq)) << 10) + hh*64 + 4*h;
  #pragma unroll
  for (int rg=0;rg<4;++rg){
    i32x2 pk;
    pk.x = (int)cvtpk(oA[rg*4+0]*inv, oA[rg*4+1]*inv);
    pk.y = (int)cvtpk(oA[rg*4+2]*inv, oA[rg*4+3]*inv);
    *(i32x2*)(ob + 8*rg) = pk;          // d-block 0: d = 8*rg + 4*h + 0..3
    pk.x = (int)cvtpk(oB[rg*4+0]*inv, oB[rg*4+1]*inv);
    pk.y = (int)cvtpk(oB[rg*4+2]*inv, oB[rg*4+3]*inv);
    *(i32x2*)(ob + 32 + 8*rg) = pk;     // d-block 1
  }
}

extern "C" void kernel_launch(void* const* d_in, const int* in_sizes, int n_in,
                              void* d_out, int out_size, void* d_ws, size_t ws_size,
                              hipStream_t stream){
  const float* q  = (const float*)d_in[0];
  const float* k  = (const float*)d_in[1];
  const float* v  = (const float*)d_in[2];
  const float* Wq = (const float*)d_in[3];
  const float* bq = (const float*)d_in[4];
  const float* Wk = (const float*)d_in[5];
  const float* bk = (const float*)d_in[6];
  const float* Wv = (const float*)d_in[7];
  const float* bv = (const float*)d_in[8];
  const float* Wo = (const float*)d_in[9];
  const float* bo = (const float*)d_in[10];
  (void)in_sizes; (void)n_in; (void)out_size; (void)ws_size;

  short* wsp = (short*)d_ws;
  const size_t MW = 1048576;          // one 1024x1024 bf16 matrix, in elements
  short* WT3 = wsp;                   // WTq, WTk, WTv contiguous
  short* WTo = wsp + 3*MW;
  short* Qh  = wsp + 4*MW;            // [B,H,S,64] bf16 (pre-scaled by 0.125*log2e)
  short* Kh  = wsp + 8*MW;            // [B,H,S,64] bf16
  short* Oh  = wsp + 12*MW;           // attention out [B*S,1024] bf16
  short* Vt  = wsp + 16*MW;           // [B,H,64,S] bf16 (written directly by gemm)

  const float QSCALE = 0.125f * 1.44269504088896f;  // fold 1/sqrt(dk) and log2(e)
  wtrans_kernel<<<dim3(256,4), 256, 0, stream>>>(Wq, Wk, Wv, Wo, wsp);
  gemm_qkv3_kernel<<<dim3(32,8,3), 512, 0, stream>>>(q, k, v, WT3, bq, bk, bv,
                                                     Qh, Kh, Vt, QSCALE);
  attn_kernel<<<dim3(16,32), 256, 0, stream>>>(Qh, Kh, Vt, Oh);
  gemm_out_kernel<<<dim3(32,8), 512, 0, stream>>>(Oh, WTo, bo, (float*)d_out);
}